// Round 12
// baseline (315.050 us; speedup 1.0000x reference)
//
#include <hip/hip_runtime.h>
#include <hip/hip_bf16.h>
#include <math.h>

#define KD 128
#define NS 4096
#define NE 4096
#define NK 128
#define NNODE (NS + NE + NK)      // 8320
#define ESE 131072
#define EEK 16384
#define NCSR (2*ESE + 2*EEK)      // 294912
#define BQ 8192
#define RP (NNODE + 1)
#define HB 32                     // CSR-build blocks per graph

typedef __attribute__((ext_vector_type(8))) short short8;   // 8 bf16 (4 VGPRs)
typedef __attribute__((ext_vector_type(4))) short short4_;  // 4 bf16 (8B)
typedef __attribute__((ext_vector_type(4))) float float4_;  // 4 fp32 acc

__device__ __forceinline__ float lrelu_(float x){ return x >= 0.f ? x : 0.2f*x; }
__device__ __forceinline__ float elu_(float x){ return x > 0.f ? x : __expf(x) - 1.f; }
__device__ __forceinline__ float sigm_(float x){ return 1.f/(1.f + __expf(-x)); }
__device__ __forceinline__ float bf2f_(unsigned short u){
  union { unsigned int i; float f; } v; v.i = ((unsigned int)u) << 16; return v.f;
}
__device__ __forceinline__ unsigned short f2b_(float x){
  __hip_bfloat16 b = __float2bfloat16(x); return *(unsigned short*)&b;
}

struct EdgePtrs { const int* s_src[3]; const int* s_dst[3]; const int* e_src[3]; const int* e_dst[3]; };

// ================= fused independent-phase kernel =================
// blocks [0,96):       CSR histogram (LDS, no global atomics)     -> part
// blocks [96,1136):    layer-1 node GEMM fp32, 8 rows/block       -> hb0/ss0/sd0
// blocks [1136,1152):  W2 transpose -> bf16 (MFMA B-operand)      -> w2b
// blocks [1152,1164):  head weights -> bf16 copy                  -> pWb
// NOTE: layer-1 stays fp32-VALU (round-5/6 lesson: closs tolerance).
// CSR build stays LDS-cursor based (round-8/9 lesson: global atomic cursors
// ping-pong cache lines across non-coherent XCD L2s — 63-72 us).
__global__ __launch_bounds__(256)
void k_fuse1(EdgePtrs ep, int* __restrict__ part,
             const float* __restrict__ W1, const float* __restrict__ a1s,
             const float* __restrict__ a1d,
             unsigned short* __restrict__ hb0, float* __restrict__ ss0,
             float* __restrict__ sd0,
             const float* __restrict__ E_stu, const float* __restrict__ E_exer,
             const float* __restrict__ E_k, const int* __restrict__ sid,
             const int* __restrict__ eid, const int* __restrict__ kid,
             const float* __restrict__ pW1, const float* __restrict__ pW2,
             const float* __restrict__ pW3, unsigned short* __restrict__ pWb,
             const float* __restrict__ W2, unsigned short* __restrict__ w2b) {
  __shared__ __align__(16) char smem[NNODE*4];   // 33 KB union
  int bid = blockIdx.x, t = threadIdx.x;

  if (bid < 3*HB) {
    // ---- CSR histogram ----
    int* hcnt = (int*)smem;
    int g = bid / HB, b = bid % HB;
    for (int i = t; i < NNODE; i += 256) hcnt[i] = 0;
    __syncthreads();
    const int* ss_ = ep.s_src[g]; const int* sd_ = ep.s_dst[g];
    const int* es_ = ep.e_src[g]; const int* ed_ = ep.e_dst[g];
    int se0 = b*(ESE/HB);
    for (int i = se0 + t; i < se0 + ESE/HB; i += 256) {
      atomicAdd(&hcnt[ss_[i]], 1);
      atomicAdd(&hcnt[NS + sd_[i]], 1);
    }
    int ek0 = b*(EEK/HB);
    for (int i = ek0 + t; i < ek0 + EEK/HB; i += 256) {
      atomicAdd(&hcnt[NS + es_[i]], 1);
      atomicAdd(&hcnt[NS + NE + ed_[i]], 1);
    }
    __syncthreads();
    int* pp = part + ((size_t)g*HB + b)*NNODE;
    for (int i = t; i < NNODE; i += 256) pp[i] = hcnt[i];
    return;
  }

  if (bid < 3*HB + NNODE/8) {
    // ---- layer-1 node GEMM (fp32 VALU, 8 rows/block for 16 waves/CU) ----
    float (*ers)[KD] = (float(*)[KD])smem;       // 4 KB of the union
    int row0 = (bid - 3*HB)*8;
    int w = t >> 6, c = t & 63;
    for (int i = t; i < 8*KD; i += 256) {
      int r = i >> 7, k = i & 127;
      int gr = row0 + r;
      const float* srow;
      if (gr < NS)           srow = E_stu  + (size_t)sid[gr]*KD;
      else if (gr < NS + NE) srow = E_exer + (size_t)eid[gr - NS]*KD;
      else                   srow = E_k    + (size_t)kid[gr - NS - NE]*KD;
      ers[r][k] = srow[k];
    }
    __syncthreads();
    float acc0[2] = {0,0}, acc1[2] = {0,0};
    #pragma unroll 2
    for (int kc = 0; kc < KD; kc += 4) {
      float wa[4], wb[4];
      #pragma unroll
      for (int j = 0; j < 4; j++) {
        wa[j] = W1[(kc + j)*KD + c];
        wb[j] = W1[(kc + j)*KD + c + 64];
      }
      #pragma unroll
      for (int r = 0; r < 2; r++) {
        float4 e = *(const float4*)&ers[w*2 + r][kc];
        acc0[r] += e.x*wa[0] + e.y*wa[1] + e.z*wa[2] + e.w*wa[3];
        acc1[r] += e.x*wb[0] + e.y*wb[1] + e.z*wb[2] + e.w*wb[3];
      }
    }
    float as1 = a1s[c], as2 = a1s[c + 64], ad1 = a1d[c], ad2 = a1d[c + 64];
    #pragma unroll
    for (int r = 0; r < 2; r++) {
      int gr = row0 + w*2 + r;
      hb0[(size_t)gr*KD + c]      = f2b_(acc0[r]);
      hb0[(size_t)gr*KD + c + 64] = f2b_(acc1[r]);
      float s = acc0[r]*as1 + acc1[r]*as2;
      float d = acc0[r]*ad1 + acc1[r]*ad2;
      #pragma unroll
      for (int off = 32; off; off >>= 1) { s += __shfl_xor(s, off); d += __shfl_xor(d, off); }
      if (c == 0) { ss0[gr] = s; sd0[gr] = d; }
    }
    return;
  }

  {
    int idx = bid - 3*HB - NNODE/8;              // 0..27
    if (idx < 16) {
      // ---- W2 transpose -> bf16 table w2b[c][k] = bf16(W2[k][c]) ----
      float (*tile)[33] = (float(*)[33])smem;
      int tx = t & 31, ty = t >> 5;              // (32,8) mapping
      int bx = (idx & 3)*32, by = (idx >> 2)*32;
      for (int j = 0; j < 32; j += 8)
        tile[ty + j][tx] = W2[(by + ty + j)*KD + bx + tx];
      __syncthreads();
      for (int j = 0; j < 32; j += 8)
        w2b[(bx + ty + j)*KD + by + tx] = f2b_(tile[tx][ty + j]);
    } else {
      // ---- head weights -> bf16 copy (no transpose: B-operand row = W row) ----
      int r = idx - 16;                          // 0..11, 4 blocks per matrix
      const float* src = r < 4 ? pW1 : (r < 8 ? pW2 : pW3);
      unsigned short* dst = pWb + (size_t)(r >> 2)*KD*KD;
      int off = (r & 3)*4096;
      for (int i = t; i < 1024; i += 256) {
        float4 v = *(const float4*)&src[off + i*4];
        short4_ s;
        s[0] = (short)f2b_(v.x); s[1] = (short)f2b_(v.y);
        s[2] = (short)f2b_(v.z); s[3] = (short)f2b_(v.w);
        *(short4_*)&dst[off + i*4] = s;
      }
    }
  }
}

// ---------- merged CSR mid-chain: sumpart + scan + boff in ONE kernel ----------
// One block per graph. Phase A: cnt[i] = sum_b part[g][b][i] (LDS, coalesced).
// Phase B: 1024-thread exclusive scan (identical algorithm, LDS-sourced).
// Phase C: boff[g][b][i] = rp[i] + prefix_b part (identical arithmetic).
// Integer-exact vs the previous 3-kernel chain; saves 2 launches + cnt_all.
__global__ __launch_bounds__(1024)
void k_csr(const int* __restrict__ part, int* __restrict__ rp_all,
           int* __restrict__ boff, float* __restrict__ clbuf) {
  __shared__ int cnt[NNODE];     // becomes rp (exclusive prefix) after phase B
  __shared__ int sums[1024];
  const int CH = (NNODE + 1023) / 1024;    // 9
  int g = blockIdx.x, t = threadIdx.x;
  if (g == 0 && t == 0) ((int*)clbuf)[32] = 0;   // closs block counter
  const int* pg = part + (size_t)g*HB*NNODE;
  // phase A: per-node degree
  for (int i = t; i < NNODE; i += 1024) cnt[i] = 0;
  __syncthreads();
  for (int b = 0; b < HB; b++)
    for (int i = t; i < NNODE; i += 1024)
      cnt[i] += pg[(size_t)b*NNODE + i];         // coalesced sweep per b
  __syncthreads();
  // phase B: scan (each thread owns chunk [t*CH, t*CH+CH))
  int base = t*CH;
  int local[CH];
  int s = 0;
  for (int j = 0; j < CH; j++) {
    int v = (base + j < NNODE) ? cnt[base + j] : 0;
    local[j] = s; s += v;
  }
  sums[t] = s; __syncthreads();
  for (int off = 1; off < 1024; off <<= 1) {
    int v = (t >= off) ? sums[t - off] : 0;
    __syncthreads();
    sums[t] += v;
    __syncthreads();
  }
  int excl = (t == 0) ? 0 : sums[t - 1];
  int* row_ptr = rp_all + g*RP;
  for (int j = 0; j < CH; j++)
    if (base + j < NNODE) {
      int r = excl + local[j];
      cnt[base + j] = r;                         // cnt now holds rp
      row_ptr[base + j] = r;
    }
  if (t == 1023) row_ptr[NNODE] = sums[1023];
  __syncthreads();                               // cross-thread reads of rp below
  // phase C: per-block cursors
  int* bg = boff + (size_t)g*HB*NNODE;
  for (int i = t; i < NNODE; i += 1024) {
    int acc = cnt[i];
    for (int b = 0; b < HB; b++) {
      bg[(size_t)b*NNODE + i] = acc;             // coalesced (threads share b)
      acc += pg[(size_t)b*NNODE + i];
    }
  }
}

// scatter via LDS cursors initialized from boff (no global atomics); col stored ushort
__global__ __launch_bounds__(256)
void k_scatter(EdgePtrs ep, const int* __restrict__ boff, unsigned short* __restrict__ col_all) {
  __shared__ int cur[NNODE];      // 33 KB live cursors
  int g = blockIdx.y, b = blockIdx.x, t = threadIdx.x;
  const int* bg = boff + ((size_t)g*HB + b)*NNODE;
  for (int i = t; i < NNODE; i += 256) cur[i] = bg[i];
  __syncthreads();
  const int* ss_ = ep.s_src[g]; const int* sd_ = ep.s_dst[g];
  const int* es_ = ep.e_src[g]; const int* ed_ = ep.e_dst[g];
  unsigned short* col = col_all + (size_t)g*NCSR;
  int se0 = b*(ESE/HB);
  for (int i = se0 + t; i < se0 + ESE/HB; i += 256) {
    int s = ss_[i], d = NS + sd_[i];
    col[atomicAdd(&cur[s], 1)] = (unsigned short)d;
    col[atomicAdd(&cur[d], 1)] = (unsigned short)s;
  }
  int ek0 = b*(EEK/HB);
  for (int i = ek0 + t; i < ek0 + EEK/HB; i += 256) {
    int s = NS + es_[i], d = NS + NE + ed_[i];
    col[atomicAdd(&cur[s], 1)] = (unsigned short)d;
    col[atomicAdd(&cur[d], 1)] = (unsigned short)s;
  }
}

// ---------- layer-2 node GEMM on MFMA (bf16 x, bf16 W2^T, fp32 acc) ----------
__global__ __launch_bounds__(256)
void k_mgemm(const unsigned short* __restrict__ X, const unsigned short* __restrict__ WT,
             const float* __restrict__ a_s, const float* __restrict__ a_d,
             unsigned short* __restrict__ hb, float* __restrict__ ss,
             float* __restrict__ sd) {
  __shared__ unsigned short As[128*KD];   // 32 KB, swizzled: row r, group g at (g ^ (r&15))
  __shared__ unsigned short Bs[128*KD];   // 32 KB (W2^T rows)
  __shared__ float ssp[128][2], sdp[128][2];
  int t = threadIdx.x;
  const unsigned short* Arow = X + (size_t)blockIdx.x*128*KD;
  #pragma unroll
  for (int j = 0; j < 8; j++) {
    int G = t + j*256;                     // linear 16B-group id, 0..2047
    int r = G >> 4, g = G & 15;
    int sw = g ^ (r & 15);
    *(float4*)&As[(r*16 + sw)*8] = *(const float4*)&Arow[(size_t)G*8];
    *(float4*)&Bs[(r*16 + sw)*8] = *(const float4*)&WT[(size_t)G*8];
  }
  __syncthreads();
  int w = t >> 6, lane = t & 63;
  int rw = (w >> 1)*64, cw = (w & 1)*64;
  int m15 = lane & 15, quad = lane >> 4;
  float4_ acc[4][4] = {};
  #pragma unroll
  for (int kq = 0; kq < 4; kq++) {
    short8 a[4], b[4];
    int g = kq*4 + quad;
    #pragma unroll
    for (int mi = 0; mi < 4; mi++) {
      int r = rw + mi*16 + m15;
      a[mi] = *(const short8*)&As[(r*16 + (g ^ (r & 15)))*8];
    }
    #pragma unroll
    for (int ni = 0; ni < 4; ni++) {
      int r = cw + ni*16 + m15;
      b[ni] = *(const short8*)&Bs[(r*16 + (g ^ (r & 15)))*8];
    }
    #pragma unroll
    for (int mi = 0; mi < 4; mi++)
      #pragma unroll
      for (int ni = 0; ni < 4; ni++)
        acc[mi][ni] = __builtin_amdgcn_mfma_f32_16x16x32_bf16(a[mi], b[ni], acc[mi][ni], 0, 0, 0);
  }
  int row0 = blockIdx.x*128;
  float asv[4], adv[4];
  #pragma unroll
  for (int ni = 0; ni < 4; ni++) {
    int gc = cw + ni*16 + m15;
    asv[ni] = a_s[gc]; adv[ni] = a_d[gc];
  }
  #pragma unroll
  for (int mi = 0; mi < 4; mi++) {
    #pragma unroll
    for (int reg = 0; reg < 4; reg++) {
      int lr = rw + mi*16 + quad*4 + reg;          // C/D: row=(lane>>4)*4+reg
      int gr = row0 + lr;
      float s = 0.f, d = 0.f;
      #pragma unroll
      for (int ni = 0; ni < 4; ni++) {
        float v = acc[mi][ni][reg];
        hb[(size_t)gr*KD + cw + ni*16 + m15] = f2b_(v);   // col=lane&15
        s += v*asv[ni]; d += v*adv[ni];
      }
      s += __shfl_xor(s, 1); d += __shfl_xor(d, 1);
      s += __shfl_xor(s, 2); d += __shfl_xor(d, 2);
      s += __shfl_xor(s, 4); d += __shfl_xor(d, 4);
      s += __shfl_xor(s, 8); d += __shfl_xor(d, 8);
      if (m15 == 0) { ssp[lr][w & 1] = s; sdp[lr][w & 1] = d; }
    }
  }
  __syncthreads();
  if (t < 128) {
    ss[row0 + t] = ssp[t][0] + ssp[t][1];
    sd[row0 + t] = sdp[t][0] + sdp[t][1];
  }
}

// ---------- segment-softmax aggregation, LDS col-staged (1-deep chain) ----------
// Round-6 lesson: __shfl across subgroups with divergent trip counts is UB.
// Wave stages its next 64 cols in a PRIVATE LDS strip; subgroup edge order
// (e = base+sub+4j, ascending) IDENTICAL to the proven strided loop.
// unroll 2: doubles loads-in-flight; accumulation statement order preserved.
__global__ __launch_bounds__(256)
void k_agg(const int* __restrict__ rp_all, const unsigned short* __restrict__ col_all,
           const unsigned short* __restrict__ hb_base, const float* __restrict__ ss,
           const float* __restrict__ sd, unsigned short* __restrict__ outb,
           unsigned short* __restrict__ eoutb, unsigned short* __restrict__ Zo, int gsel) {
  __shared__ unsigned short colsh[4][64];   // per-wave private strip
  int wib = threadIdx.x >> 6;
  int wv = blockIdx.x*4 + wib;
  int lane = threadIdx.x & 63;
  if (wv >= 3*NNODE) return;
  int g = wv / NNODE, node = wv - g*NNODE;
  bool layer2 = (gsel == -2);
  if (layer2 && node >= NS + NE) return;        // k rows unused after layer 2
  const int* rp = rp_all + g*RP;
  const unsigned short* cl = col_all + (size_t)g*NCSR;
  const unsigned short* hgb = layer2 ? hb_base + (size_t)g*NNODE*KD : hb_base;
  const float* ssg = layer2 ? ss + g*NNODE : ss;
  const float* sdg = layer2 ? sd + g*NNODE : sd;
  int e0 = rp[node], e1 = rp[node + 1];
  float sdv = sdg[node];
  int sub = lane >> 4;       // edge subgroup 0..3
  int fl  = lane & 15;       // feature lane: features fl*8 .. fl*8+7
  float l = 0.f;
  float A[8] = {0,0,0,0,0,0,0,0};
  for (int base = e0; base < e1; base += 64) {
    int cnt = e1 - base; if (cnt > 64) cnt = 64;
    if (lane < cnt) colsh[wib][lane] = cl[base + lane];  // coalesced col preload
    int tj = (cnt - sub + 3) >> 2;                       // edges sub+4j, j<tj
    #pragma unroll 2
    for (int j = 0; j < tj; j++) {
      int o = colsh[wib][sub + 4*j];                     // LDS, 1-deep chain
      float pj = __expf(lrelu_(ssg[o] + sdv));
      l += pj;
      short8 mv = *(const short8*)&hgb[(size_t)o*KD + fl*8];   // 16 lanes x 16B = 256B row
      #pragma unroll
      for (int q = 0; q < 8; q++)
        A[q] += pj * bf2f_((unsigned short)mv[q]);
    }
  }
  l += __shfl_xor(l, 16); l += __shfl_xor(l, 32);
  #pragma unroll
  for (int q = 0; q < 8; q++) {
    A[q] += __shfl_xor(A[q], 16);
    A[q] += __shfl_xor(A[q], 32);
  }
  float inv = 1.f/(l + 1e-16f);
  float av[8];
  #pragma unroll
  for (int q = 0; q < 8; q++) av[q] = elu_(A[q]*inv);
  if (!layer2) {
    if (sub == 0) {
      short8 sv;
      #pragma unroll
      for (int q = 0; q < 8; q++) sv[q] = (short)f2b_(av[q]);
      *(short8*)&outb[(size_t)wv*KD + fl*8] = sv;
    }
    return;
  }
  if (g == 0) {
    if (sub == 0) {
      short8 sv;
      #pragma unroll
      for (int q = 0; q < 8; q++) sv[q] = (short)f2b_(av[q]);
      *(short8*)&eoutb[(size_t)node*KD + fl*8] = sv;
    }
  } else {
    float nrm = av[0]*av[0] + av[1]*av[1] + av[2]*av[2] + av[3]*av[3]
              + av[4]*av[4] + av[5]*av[5] + av[6]*av[6] + av[7]*av[7];
    #pragma unroll
    for (int off = 1; off <= 8; off <<= 1) nrm += __shfl_xor(nrm, off);
    float invn = 1.f/(sqrtf(nrm) + 1e-12f);
    if (sub == 0) {
      short8 sv;
      #pragma unroll
      for (int q = 0; q < 8; q++) sv[q] = (short)f2b_(av[q]*invn);
      *(short8*)&Zo[((size_t)(g - 1)*8192 + node)*KD + fl*8] = sv;
    }
  }
}

// ---------- fused: MFMA prediction head (blocks [0,256)) + sim GEMM (rest) ----------
__global__ __launch_bounds__(256)
void k_simhead(const unsigned short* __restrict__ Z, float* __restrict__ rsp,
               float* __restrict__ csp, float* __restrict__ dg_all,
               const unsigned short* __restrict__ pWb,
               const float* __restrict__ pb, const float* __restrict__ knr,
               float* __restrict__ out, const unsigned short* __restrict__ eoutb,
               const int* __restrict__ i1, const int* __restrict__ i2) {
  __shared__ __align__(16) unsigned short U[2*128*KD];   // 64 KB union
  int bid = blockIdx.x, t = threadIdx.x;

  if (bid < BQ/32) {
    // ================= head: 3 chained 32x128x128 bf16 GEMMs =================
    unsigned short* At = U;                 // 8 KB
    unsigned short* Bt = U + 32*KD;         // 8 KB
    unsigned short* Xt = U + 64*KD;         // 8 KB
    float (*nump)[2] = (float(*)[2])(U + 96*KD);
    float (*denp)[2] = (float(*)[2])(U + 96*KD + 128);   // +256 B
    int row0 = bid*32;
    for (int i = t; i < 512; i += 256) {    // 512 8-elem groups per tile
      int r = i >> 4, g = i & 15;
      int sw = g ^ (r & 15);
      *(short8*)&At[(r*16 + sw)*8] =
          *(const short8*)&eoutb[(size_t)i1[row0 + r]*KD + g*8];
      *(short8*)&Bt[(r*16 + sw)*8] =
          *(const short8*)&eoutb[(size_t)(NS + i2[row0 + r])*KD + g*8];
    }
    __syncthreads();
    int w = t >> 6, lane = t & 63;
    int rw = (w >> 1)*16, cw = (w & 1)*64;     // wave -> (16-row, 64-col) quadrant
    int m15 = lane & 15, quad = lane >> 4;
    const unsigned short* W1g = pWb;
    const unsigned short* W2g = pWb + KD*KD;
    const unsigned short* W3g = pWb + 2*KD*KD;
    float4_ accP[4] = {}, accD[4] = {};
    #pragma unroll
    for (int kq = 0; kq < 4; kq++) {
      int g = kq*4 + quad;
      int ra = rw + m15;
      short8 a1 = *(const short8*)&At[(ra*16 + (g ^ (ra & 15)))*8];
      short8 a2 = *(const short8*)&Bt[(ra*16 + (g ^ (ra & 15)))*8];
      #pragma unroll
      for (int ni = 0; ni < 4; ni++) {
        int rb = cw + ni*16 + m15;
        short8 b1 = *(const short8*)&W1g[(size_t)rb*KD + g*8];
        short8 b2 = *(const short8*)&W2g[(size_t)rb*KD + g*8];
        accP[ni] = __builtin_amdgcn_mfma_f32_16x16x32_bf16(a1, b1, accP[ni], 0, 0, 0);
        accD[ni] = __builtin_amdgcn_mfma_f32_16x16x32_bf16(a2, b2, accD[ni], 0, 0, 0);
      }
    }
    #pragma unroll
    for (int ni = 0; ni < 4; ni++) {
      #pragma unroll
      for (int reg = 0; reg < 4; reg++) {
        int lr = rw + quad*4 + reg;
        int col = cw + ni*16 + m15;
        float diff = sigm_(accP[ni][reg]) - sigm_(accD[ni][reg]);
        int g2 = col >> 3;
        Xt[(lr*16 + (g2 ^ (lr & 15)))*8 + (col & 7)] = f2b_(diff);
      }
    }
    __syncthreads();
    float4_ accO[4] = {};
    #pragma unroll
    for (int kq = 0; kq < 4; kq++) {
      int g = kq*4 + quad;
      int ra = rw + m15;
      short8 a = *(const short8*)&Xt[(ra*16 + (g ^ (ra & 15)))*8];
      #pragma unroll
      for (int ni = 0; ni < 4; ni++) {
        int rb = cw + ni*16 + m15;
        short8 b = *(const short8*)&W3g[(size_t)rb*KD + g*8];
        accO[ni] = __builtin_amdgcn_mfma_f32_16x16x32_bf16(a, b, accO[ni], 0, 0, 0);
      }
    }
    float pbv[4];
    #pragma unroll
    for (int ni = 0; ni < 4; ni++) pbv[ni] = pb[cw + ni*16 + m15];
    #pragma unroll
    for (int reg = 0; reg < 4; reg++) {
      int lr = rw + quad*4 + reg;
      int gr = row0 + lr;
      float num = 0.f, den = 0.f;
      #pragma unroll
      for (int ni = 0; ni < 4; ni++) {
        float kr = knr[(size_t)gr*KD + cw + ni*16 + m15];
        float o = sigm_(accO[ni][reg] + pbv[ni]);
        num += o*kr; den += kr;
      }
      num += __shfl_xor(num, 1); den += __shfl_xor(den, 1);
      num += __shfl_xor(num, 2); den += __shfl_xor(den, 2);
      num += __shfl_xor(num, 4); den += __shfl_xor(den, 4);
      num += __shfl_xor(num, 8); den += __shfl_xor(den, 8);
      if (m15 == 0) { nump[lr][w & 1] = num; denp[lr][w & 1] = den; }
    }
    __syncthreads();
    if (t < 32)
      out[row0 + t] = (nump[t][0] + nump[t][1]) / (denp[t][0] + denp[t][1]);
    return;
  }

  // ================= sim: bf16 MFMA similarity GEMM =================
  {
    unsigned short* As = U;
    unsigned short* Bs = U + 128*KD;
    int sb = bid - BQ/32;
    int bx = sb & 31, by = (sb >> 5) & 31, z = sb >> 10;
    const unsigned short* Arow = Z + ((size_t)z*NS + (size_t)bx*128)*KD;
    const unsigned short* Brow = Z + ((size_t)8192 + (size_t)z*NS + (size_t)by*128)*KD;
    #pragma unroll
    for (int j = 0; j < 8; j++) {
      int G = t + j*256;                     // linear 16B-group id, 0..2047
      int r = G >> 4, g = G & 15;
      int sw = g ^ (r & 15);
      *(float4*)&As[(r*16 + sw)*8] = *(const float4*)&Arow[(size_t)G*8];
      *(float4*)&Bs[(r*16 + sw)*8] = *(const float4*)&Brow[(size_t)G*8];
    }
    __syncthreads();
    int w = t >> 6, lane = t & 63;
    int rw = (w >> 1)*64, cw = (w & 1)*64;
    int m15 = lane & 15, quad = lane >> 4;
    float4_ acc[4][4] = {};
    #pragma unroll
    for (int kq = 0; kq < 4; kq++) {
      short8 a[4], b[4];
      int g = kq*4 + quad;
      #pragma unroll
      for (int mi = 0; mi < 4; mi++) {
        int r = rw + mi*16 + m15;
        a[mi] = *(const short8*)&As[(r*16 + (g ^ (r & 15)))*8];
      }
      #pragma unroll
      for (int ni = 0; ni < 4; ni++) {
        int r = cw + ni*16 + m15;
        b[ni] = *(const short8*)&Bs[(r*16 + (g ^ (r & 15)))*8];
      }
      #pragma unroll
      for (int mi = 0; mi < 4; mi++)
        #pragma unroll
        for (int ni = 0; ni < 4; ni++)
          acc[mi][ni] = __builtin_amdgcn_mfma_f32_16x16x32_bf16(a[mi], b[ni], acc[mi][ni], 0, 0, 0);
    }
    int i0 = bx*128, j0 = by*128;
    float* diag = dg_all + z*NS;
    float* rrow = rsp + ((size_t)z*64 + by*2 + (w & 1))*NS;
    float* crow = csp + ((size_t)z*64 + bx*2 + (w >> 1))*NS;
    float cs[4] = {0,0,0,0};
    #pragma unroll
    for (int mi = 0; mi < 4; mi++) {
      float rs[4] = {0,0,0,0};
      #pragma unroll
      for (int ni = 0; ni < 4; ni++) {
        #pragma unroll
        for (int reg = 0; reg < 4; reg++) {
          float sim2 = acc[mi][ni][reg]*2.0f;
          int gi = i0 + rw + mi*16 + quad*4 + reg;     // C/D: row=(lane>>4)*4+reg
          int gj = j0 + cw + ni*16 + m15;              //      col=lane&15
          if (gi == gj) diag[gi] = sim2;
          float e = __expf(sim2);
          rs[reg] += e; cs[ni] += e;
        }
      }
      #pragma unroll
      for (int reg = 0; reg < 4; reg++) {
        float v = rs[reg];
        v += __shfl_xor(v, 1); v += __shfl_xor(v, 2);
        v += __shfl_xor(v, 4); v += __shfl_xor(v, 8);
        if (m15 == 0) rrow[i0 + rw + mi*16 + quad*4 + reg] = v;
      }
    }
    #pragma unroll
    for (int ni = 0; ni < 4; ni++) {
      float v = cs[ni];
      v += __shfl_xor(v, 16); v += __shfl_xor(v, 32);
      if (quad == 0) crow[j0 + cw + ni*16 + m15] = v;
    }
  }
}

// reduce partials -> closs. DETERMINISTIC finalize: slot publish + last-block
// ordered tree reduce (same numerics as the round-2/3 passing path).
__global__ void k_lred(const float* __restrict__ rsp, const float* __restrict__ csp,
                       const float* __restrict__ dg_all, float* __restrict__ out,
                       float* __restrict__ clbuf) {
  __shared__ float red[256];
  __shared__ int lastflag;
  int z = blockIdx.y;
  int i = blockIdx.x*256 + threadIdx.x;
  float rs = 0.f, cs = 0.f;
  for (int s = 0; s < 64; s++) {
    rs += rsp[((size_t)z*64 + s)*NS + i];
    cs += csp[((size_t)z*64 + s)*NS + i];
  }
  float v = logf(rs) + logf(cs) - 2.f*dg_all[z*NS + i];
  red[threadIdx.x] = v; __syncthreads();
  for (int off = 128; off; off >>= 1) {
    if (threadIdx.x < off) red[threadIdx.x] += red[threadIdx.x + off];
    __syncthreads();
  }
  if (threadIdx.x == 0) {
    atomicExch(&clbuf[z*16 + blockIdx.x], red[0]);   // coherent slot publish
    __threadfence();
    int old = atomicAdd((int*)clbuf + 32, 1);
    lastflag = (old == 31) ? 1 : 0;
  }
  __syncthreads();
  if (lastflag && threadIdx.x < 64) {
    int lane = threadIdx.x;
    float pv = (lane < 32) ? atomicAdd(&clbuf[lane], 0.0f) : 0.f;  // atomic load
    #pragma unroll
    for (int off = 32; off; off >>= 1) pv += __shfl_xor(pv, off);
    if (lane == 0) out[BQ] = 0.1f*pv/(float)NS;
  }
}

extern "C" void kernel_launch(void* const* d_in, const int* in_sizes, int n_in,
                              void* d_out, int out_size, void* d_ws, size_t ws_size,
                              hipStream_t stream) {
  const float* E_stu  = (const float*)d_in[0];
  const float* E_exer = (const float*)d_in[1];
  const float* E_k    = (const float*)d_in[2];
  const float* W1  = (const float*)d_in[3];
  const float* a1s = (const float*)d_in[4];
  const float* a1d = (const float*)d_in[5];
  const float* W2  = (const float*)d_in[6];
  const float* a2s = (const float*)d_in[7];
  const float* a2d = (const float*)d_in[8];
  const float* pW1 = (const float*)d_in[9];
  const float* pW2 = (const float*)d_in[10];
  const float* pW3 = (const float*)d_in[11];
  const float* pb3 = (const float*)d_in[12];
  const float* kn_r = (const float*)d_in[13];
  const int* stu_ids  = (const int*)d_in[14];
  const int* exer_ids = (const int*)d_in[15];
  const int* k_ids    = (const int*)d_in[16];
  EdgePtrs ep;
  for (int g = 0; g < 3; g++) {
    ep.s_src[g] = (const int*)d_in[17 + g*4];
    ep.s_dst[g] = (const int*)d_in[18 + g*4];
    ep.e_src[g] = (const int*)d_in[19 + g*4];
    ep.e_dst[g] = (const int*)d_in[20 + g*4];
  }
  const int* stu_index  = (const int*)d_in[29];
  const int* exer_index = (const int*)d_in[30];
  float* out = (float*)d_out;   // [0..8191] predictions, [8192] closs

  // ---- workspace carve ----
  char* p = (char*)d_ws;
  auto carve = [&](size_t bytes) -> char* {
    char* r = p; p += (bytes + 255) & ~(size_t)255; return r;
  };
  const size_t NODE_F = (size_t)NNODE*KD;
  float* ssb = (float*)carve((size_t)8*NNODE*4);
  float* ss0 = ssb,            *sd0 = ssb + NNODE;
  float* ss3 = ssb + 2*NNODE,  *sd3 = ssb + 5*NNODE;
  unsigned short* hb0 = (unsigned short*)carve(NODE_F*2);        // layer-1 h (shared)
  unsigned short* hb3 = (unsigned short*)carve(3*NODE_F*2);      // layer-2 h x3
  // time-multiplexed: CSR partials (6.4 MB) -> layer-1 agg bf16 out (6.4 MB)
  char* Creg = carve((size_t)8*HB*NNODE*4);
  int*   part = (int*)Creg;                       // part[3][HB][NNODE]
  int*   boff = (int*)Creg + (size_t)3*HB*NNODE;  // boff[3][HB][NNODE]
  unsigned short* etb = (unsigned short*)Creg;    // layer-1 agg out, bf16 [3*NNODE][KD]
  unsigned short* eoutb = (unsigned short*)carve((size_t)(NS + NE)*KD*2);  // g0 layer-2 out (bf16)
  int* rp_all  = (int*)carve((size_t)3*RP*4);
  unsigned short* col_all = (unsigned short*)carve((size_t)3*NCSR*2);
  unsigned short* pWb = (unsigned short*)carve((size_t)3*KD*KD*2);  // bf16 head W x3
  float* rsp = (float*)carve((size_t)2*64*NS*4);   // rowsum partials
  float* csp = (float*)carve((size_t)2*64*NS*4);   // colsum partials
  float* dg_all = (float*)carve((size_t)2*NS*4);
  float* clbuf = (float*)carve(256);               // [0..31] partials, [32] counter
  unsigned short* Z = (unsigned short*)carve((size_t)2*8192*KD*2);  // bf16 Z1|Z2
  unsigned short* w2b = (unsigned short*)carve((size_t)KD*KD*2);    // bf16 W2^T [c][k]

  // ---- fused: CSR hist ∪ layer-1 fp32 GEMM (8-row blocks) ∪ weight converts ----
  k_fuse1<<<3*HB + NNODE/8 + 16 + 12, 256, 0, stream>>>(
      ep, part, W1, a1s, a1d, hb0, ss0, sd0,
      E_stu, E_exer, E_k, stu_ids, exer_ids, k_ids,
      pW1, pW2, pW3, pWb, W2, w2b);

  // ---- merged CSR mid-chain (sumpart+scan+boff in one kernel, 3 blocks) ----
  k_csr<<<3, 1024, 0, stream>>>(part, rp_all, boff, clbuf);
  k_scatter<<<dim3(HB, 3), 256, 0, stream>>>(ep, boff, col_all);

  // ---- GAT layer 1 aggregation (batched) ----
  k_agg<<<3*NNODE/4, 256, 0, stream>>>(rp_all, col_all, hb0, ss0, sd0, etb,
                                       nullptr, nullptr, -1);

  // ---- GAT layer 2 (bf16 MFMA node GEMM; batched agg) ----
  k_mgemm<<<3*NNODE/128, 256, 0, stream>>>(etb, w2b, a2s, a2d, hb3, ss3, sd3);
  k_agg<<<3*NNODE/4, 256, 0, stream>>>(rp_all, col_all, hb3, ss3, sd3, nullptr,
                                       eoutb, Z, -2);

  // ---- fused: prediction head (256 blocks) ∥ sim GEMM (2048 blocks) ----
  k_simhead<<<BQ/32 + 2048, 256, 0, stream>>>(Z, rsp, csp, dg_all,
                                              pWb, pb3, kn_r, out, eoutb,
                                              stu_index, exer_index);

  // ---- closs reduce + deterministic last-block finalize ----
  k_lred<<<dim3(16, 2), 256, 0, stream>>>(rsp, csp, dg_all, out, clbuf);
}

// Round 13
// 263.155 us; speedup vs baseline: 1.1972x; 1.1972x over previous
//
#include <hip/hip_runtime.h>
#include <hip/hip_bf16.h>
#include <math.h>

#define KD 128
#define NS 4096
#define NE 4096
#define NK 128
#define NNODE (NS + NE + NK)      // 8320
#define ESE 131072
#define EEK 16384
#define NCSR (2*ESE + 2*EEK)      // 294912
#define BQ 8192
#define RP (NNODE + 1)
#define HB 32                     // CSR-build blocks per graph

typedef __attribute__((ext_vector_type(8))) short short8;   // 8 bf16 (4 VGPRs)
typedef __attribute__((ext_vector_type(4))) short short4_;  // 4 bf16 (8B)
typedef __attribute__((ext_vector_type(4))) float float4_;  // 4 fp32 acc

__device__ __forceinline__ float lrelu_(float x){ return x >= 0.f ? x : 0.2f*x; }
__device__ __forceinline__ float elu_(float x){ return x > 0.f ? x : __expf(x) - 1.f; }
__device__ __forceinline__ float sigm_(float x){ return 1.f/(1.f + __expf(-x)); }
__device__ __forceinline__ float bf2f_(unsigned short u){
  union { unsigned int i; float f; } v; v.i = ((unsigned int)u) << 16; return v.f;
}
__device__ __forceinline__ unsigned short f2b_(float x){
  __hip_bfloat16 b = __float2bfloat16(x); return *(unsigned short*)&b;
}

struct EdgePtrs { const int* s_src[3]; const int* s_dst[3]; const int* e_src[3]; const int* e_dst[3]; };

// ================= fused independent-phase kernel =================
// blocks [0,96):       CSR histogram (LDS, no global atomics)     -> part
// blocks [96,1136):    layer-1 node GEMM fp32, 8 rows/block       -> hb0/ss0/sd0
// blocks [1136,1152):  W2 transpose -> bf16 (MFMA B-operand)      -> w2b
// blocks [1152,1164):  head weights -> bf16 copy                  -> pWb
// NOTE: layer-1 stays fp32-VALU (round-5/6 lesson: closs tolerance).
// CSR build stays LDS-cursor based (round-8/9: global atomic cursors ping-pong
// across non-coherent XCD L2s). CSR mid-chain stays 3 kernels (round-12: a
// 3-block merged kernel is single-CU-BW-bound at 68 us — never serialize
// MB-scale traffic through O(1) blocks to save launches).
__global__ __launch_bounds__(256)
void k_fuse1(EdgePtrs ep, int* __restrict__ part,
             const float* __restrict__ W1, const float* __restrict__ a1s,
             const float* __restrict__ a1d,
             unsigned short* __restrict__ hb0, float* __restrict__ ss0,
             float* __restrict__ sd0,
             const float* __restrict__ E_stu, const float* __restrict__ E_exer,
             const float* __restrict__ E_k, const int* __restrict__ sid,
             const int* __restrict__ eid, const int* __restrict__ kid,
             const float* __restrict__ pW1, const float* __restrict__ pW2,
             const float* __restrict__ pW3, unsigned short* __restrict__ pWb,
             const float* __restrict__ W2, unsigned short* __restrict__ w2b) {
  __shared__ __align__(16) char smem[NNODE*4];   // 33 KB union
  int bid = blockIdx.x, t = threadIdx.x;

  if (bid < 3*HB) {
    // ---- CSR histogram ----
    int* hcnt = (int*)smem;
    int g = bid / HB, b = bid % HB;
    for (int i = t; i < NNODE; i += 256) hcnt[i] = 0;
    __syncthreads();
    const int* ss_ = ep.s_src[g]; const int* sd_ = ep.s_dst[g];
    const int* es_ = ep.e_src[g]; const int* ed_ = ep.e_dst[g];
    int se0 = b*(ESE/HB);
    for (int i = se0 + t; i < se0 + ESE/HB; i += 256) {
      atomicAdd(&hcnt[ss_[i]], 1);
      atomicAdd(&hcnt[NS + sd_[i]], 1);
    }
    int ek0 = b*(EEK/HB);
    for (int i = ek0 + t; i < ek0 + EEK/HB; i += 256) {
      atomicAdd(&hcnt[NS + es_[i]], 1);
      atomicAdd(&hcnt[NS + NE + ed_[i]], 1);
    }
    __syncthreads();
    int* pp = part + ((size_t)g*HB + b)*NNODE;
    for (int i = t; i < NNODE; i += 256) pp[i] = hcnt[i];
    return;
  }

  if (bid < 3*HB + NNODE/8) {
    // ---- layer-1 node GEMM (fp32 VALU, 8 rows/block for 16 waves/CU) ----
    float (*ers)[KD] = (float(*)[KD])smem;       // 4 KB of the union
    int row0 = (bid - 3*HB)*8;
    int w = t >> 6, c = t & 63;
    for (int i = t; i < 8*KD; i += 256) {
      int r = i >> 7, k = i & 127;
      int gr = row0 + r;
      const float* srow;
      if (gr < NS)           srow = E_stu  + (size_t)sid[gr]*KD;
      else if (gr < NS + NE) srow = E_exer + (size_t)eid[gr - NS]*KD;
      else                   srow = E_k    + (size_t)kid[gr - NS - NE]*KD;
      ers[r][k] = srow[k];
    }
    __syncthreads();
    float acc0[2] = {0,0}, acc1[2] = {0,0};
    #pragma unroll 2
    for (int kc = 0; kc < KD; kc += 4) {
      float wa[4], wb[4];
      #pragma unroll
      for (int j = 0; j < 4; j++) {
        wa[j] = W1[(kc + j)*KD + c];
        wb[j] = W1[(kc + j)*KD + c + 64];
      }
      #pragma unroll
      for (int r = 0; r < 2; r++) {
        float4 e = *(const float4*)&ers[w*2 + r][kc];
        acc0[r] += e.x*wa[0] + e.y*wa[1] + e.z*wa[2] + e.w*wa[3];
        acc1[r] += e.x*wb[0] + e.y*wb[1] + e.z*wb[2] + e.w*wb[3];
      }
    }
    float as1 = a1s[c], as2 = a1s[c + 64], ad1 = a1d[c], ad2 = a1d[c + 64];
    #pragma unroll
    for (int r = 0; r < 2; r++) {
      int gr = row0 + w*2 + r;
      hb0[(size_t)gr*KD + c]      = f2b_(acc0[r]);
      hb0[(size_t)gr*KD + c + 64] = f2b_(acc1[r]);
      float s = acc0[r]*as1 + acc1[r]*as2;
      float d = acc0[r]*ad1 + acc1[r]*ad2;
      #pragma unroll
      for (int off = 32; off; off >>= 1) { s += __shfl_xor(s, off); d += __shfl_xor(d, off); }
      if (c == 0) { ss0[gr] = s; sd0[gr] = d; }
    }
    return;
  }

  {
    int idx = bid - 3*HB - NNODE/8;              // 0..27
    if (idx < 16) {
      // ---- W2 transpose -> bf16 table w2b[c][k] = bf16(W2[k][c]) ----
      float (*tile)[33] = (float(*)[33])smem;
      int tx = t & 31, ty = t >> 5;              // (32,8) mapping
      int bx = (idx & 3)*32, by = (idx >> 2)*32;
      for (int j = 0; j < 32; j += 8)
        tile[ty + j][tx] = W2[(by + ty + j)*KD + bx + tx];
      __syncthreads();
      for (int j = 0; j < 32; j += 8)
        w2b[(bx + ty + j)*KD + by + tx] = f2b_(tile[tx][ty + j]);
    } else {
      // ---- head weights -> bf16 copy (no transpose: B-operand row = W row) ----
      int r = idx - 16;                          // 0..11, 4 blocks per matrix
      const float* src = r < 4 ? pW1 : (r < 8 ? pW2 : pW3);
      unsigned short* dst = pWb + (size_t)(r >> 2)*KD*KD;
      int off = (r & 3)*4096;
      for (int i = t; i < 1024; i += 256) {
        float4 v = *(const float4*)&src[off + i*4];
        short4_ s;
        s[0] = (short)f2b_(v.x); s[1] = (short)f2b_(v.y);
        s[2] = (short)f2b_(v.z); s[3] = (short)f2b_(v.w);
        *(short4_*)&dst[off + i*4] = s;
      }
    }
  }
}

// thread-per-node partial-sum: cnt[g][n] = sum_b part[g][b][n]  (coalesced over n)
__global__ void k_sumpart(const int* __restrict__ part, int* __restrict__ cnt_all) {
  int idx = blockIdx.x*256 + threadIdx.x;
  if (idx >= 3*NNODE) return;
  int g = idx / NNODE, n = idx - g*NNODE;
  const int* pg = part + (size_t)g*HB*NNODE + n;
  int s = 0;
  #pragma unroll
  for (int b = 0; b < HB; b++) s += pg[(size_t)b*NNODE];
  cnt_all[idx] = s;
}

// per-graph single-block scan of cnt -> row_ptr
__global__ void k_scan(const int* __restrict__ cnt_all, int* __restrict__ rp_all) {
  __shared__ int sums[1024];
  const int CH = (NNODE + 1023) / 1024;    // 9
  int g = blockIdx.x, t = threadIdx.x;
  const int* cnt = cnt_all + g*NNODE;
  int* row_ptr = rp_all + g*RP;
  int base = t*CH;
  int local[CH];
  int s = 0;
  for (int j = 0; j < CH; j++) {
    int v = (base + j < NNODE) ? cnt[base + j] : 0;
    local[j] = s; s += v;
  }
  sums[t] = s; __syncthreads();
  for (int off = 1; off < 1024; off <<= 1) {
    int v = (t >= off) ? sums[t - off] : 0;
    __syncthreads();
    sums[t] += v;
    __syncthreads();
  }
  int excl = (t == 0) ? 0 : sums[t - 1];
  for (int j = 0; j < CH; j++)
    if (base + j < NNODE) row_ptr[base + j] = excl + local[j];
  if (t == 1023) row_ptr[NNODE] = sums[1023];
}

// thread-per-node: emit per-block cursors boff[g][b][n]; idx 0 zeroes closs counter
__global__ void k_boff(const int* __restrict__ part, const int* __restrict__ rp_all,
                       int* __restrict__ boff, float* __restrict__ clbuf) {
  int idx = blockIdx.x*256 + threadIdx.x;
  if (idx == 0) ((int*)clbuf)[32] = 0;     // counter; slots [0..31] written by exch
  if (idx >= 3*NNODE) return;
  int g = idx / NNODE, n = idx - g*NNODE;
  const int* pg = part + (size_t)g*HB*NNODE + n;
  int* bg = boff + (size_t)g*HB*NNODE + n;
  int acc = rp_all[g*RP + n];
  #pragma unroll
  for (int b = 0; b < HB; b++) {
    bg[(size_t)b*NNODE] = acc;
    acc += pg[(size_t)b*NNODE];
  }
}

// scatter via LDS cursors initialized from boff (no global atomics); col stored ushort
__global__ __launch_bounds__(256)
void k_scatter(EdgePtrs ep, const int* __restrict__ boff, unsigned short* __restrict__ col_all) {
  __shared__ int cur[NNODE];      // 33 KB live cursors
  int g = blockIdx.y, b = blockIdx.x, t = threadIdx.x;
  const int* bg = boff + ((size_t)g*HB + b)*NNODE;
  for (int i = t; i < NNODE; i += 256) cur[i] = bg[i];
  __syncthreads();
  const int* ss_ = ep.s_src[g]; const int* sd_ = ep.s_dst[g];
  const int* es_ = ep.e_src[g]; const int* ed_ = ep.e_dst[g];
  unsigned short* col = col_all + (size_t)g*NCSR;
  int se0 = b*(ESE/HB);
  for (int i = se0 + t; i < se0 + ESE/HB; i += 256) {
    int s = ss_[i], d = NS + sd_[i];
    col[atomicAdd(&cur[s], 1)] = (unsigned short)d;
    col[atomicAdd(&cur[d], 1)] = (unsigned short)s;
  }
  int ek0 = b*(EEK/HB);
  for (int i = ek0 + t; i < ek0 + EEK/HB; i += 256) {
    int s = NS + es_[i], d = NS + NE + ed_[i];
    col[atomicAdd(&cur[s], 1)] = (unsigned short)d;
    col[atomicAdd(&cur[d], 1)] = (unsigned short)s;
  }
}

// ---------- layer-2 node GEMM on MFMA (bf16 x, bf16 W2^T, fp32 acc) ----------
__global__ __launch_bounds__(256)
void k_mgemm(const unsigned short* __restrict__ X, const unsigned short* __restrict__ WT,
             const float* __restrict__ a_s, const float* __restrict__ a_d,
             unsigned short* __restrict__ hb, float* __restrict__ ss,
             float* __restrict__ sd) {
  __shared__ unsigned short As[128*KD];   // 32 KB, swizzled: row r, group g at (g ^ (r&15))
  __shared__ unsigned short Bs[128*KD];   // 32 KB (W2^T rows)
  __shared__ float ssp[128][2], sdp[128][2];
  int t = threadIdx.x;
  const unsigned short* Arow = X + (size_t)blockIdx.x*128*KD;
  #pragma unroll
  for (int j = 0; j < 8; j++) {
    int G = t + j*256;                     // linear 16B-group id, 0..2047
    int r = G >> 4, g = G & 15;
    int sw = g ^ (r & 15);
    *(float4*)&As[(r*16 + sw)*8] = *(const float4*)&Arow[(size_t)G*8];
    *(float4*)&Bs[(r*16 + sw)*8] = *(const float4*)&WT[(size_t)G*8];
  }
  __syncthreads();
  int w = t >> 6, lane = t & 63;
  int rw = (w >> 1)*64, cw = (w & 1)*64;
  int m15 = lane & 15, quad = lane >> 4;
  float4_ acc[4][4] = {};
  #pragma unroll
  for (int kq = 0; kq < 4; kq++) {
    short8 a[4], b[4];
    int g = kq*4 + quad;
    #pragma unroll
    for (int mi = 0; mi < 4; mi++) {
      int r = rw + mi*16 + m15;
      a[mi] = *(const short8*)&As[(r*16 + (g ^ (r & 15)))*8];
    }
    #pragma unroll
    for (int ni = 0; ni < 4; ni++) {
      int r = cw + ni*16 + m15;
      b[ni] = *(const short8*)&Bs[(r*16 + (g ^ (r & 15)))*8];
    }
    #pragma unroll
    for (int mi = 0; mi < 4; mi++)
      #pragma unroll
      for (int ni = 0; ni < 4; ni++)
        acc[mi][ni] = __builtin_amdgcn_mfma_f32_16x16x32_bf16(a[mi], b[ni], acc[mi][ni], 0, 0, 0);
  }
  int row0 = blockIdx.x*128;
  float asv[4], adv[4];
  #pragma unroll
  for (int ni = 0; ni < 4; ni++) {
    int gc = cw + ni*16 + m15;
    asv[ni] = a_s[gc]; adv[ni] = a_d[gc];
  }
  #pragma unroll
  for (int mi = 0; mi < 4; mi++) {
    #pragma unroll
    for (int reg = 0; reg < 4; reg++) {
      int lr = rw + mi*16 + quad*4 + reg;          // C/D: row=(lane>>4)*4+reg
      int gr = row0 + lr;
      float s = 0.f, d = 0.f;
      #pragma unroll
      for (int ni = 0; ni < 4; ni++) {
        float v = acc[mi][ni][reg];
        hb[(size_t)gr*KD + cw + ni*16 + m15] = f2b_(v);   // col=lane&15
        s += v*asv[ni]; d += v*adv[ni];
      }
      s += __shfl_xor(s, 1); d += __shfl_xor(d, 1);
      s += __shfl_xor(s, 2); d += __shfl_xor(d, 2);
      s += __shfl_xor(s, 4); d += __shfl_xor(d, 4);
      s += __shfl_xor(s, 8); d += __shfl_xor(d, 8);
      if (m15 == 0) { ssp[lr][w & 1] = s; sdp[lr][w & 1] = d; }
    }
  }
  __syncthreads();
  if (t < 128) {
    ss[row0 + t] = ssp[t][0] + ssp[t][1];
    sd[row0 + t] = sdp[t][0] + sdp[t][1];
  }
}

// ---------- segment-softmax aggregation, LDS col-staged (1-deep chain) ----------
// Wave stages its next 64 cols in a PRIVATE LDS strip (no cross-lane ops);
// subgroup edge order (e = base+sub+4j, ascending) IDENTICAL to the proven
// strided loop. unroll 2: more loads in flight; statement order preserved.
__global__ __launch_bounds__(256)
void k_agg(const int* __restrict__ rp_all, const unsigned short* __restrict__ col_all,
           const unsigned short* __restrict__ hb_base, const float* __restrict__ ss,
           const float* __restrict__ sd, unsigned short* __restrict__ outb,
           unsigned short* __restrict__ eoutb, unsigned short* __restrict__ Zo, int gsel) {
  __shared__ unsigned short colsh[4][64];   // per-wave private strip
  int wib = threadIdx.x >> 6;
  int wv = blockIdx.x*4 + wib;
  int lane = threadIdx.x & 63;
  if (wv >= 3*NNODE) return;
  int g = wv / NNODE, node = wv - g*NNODE;
  bool layer2 = (gsel == -2);
  if (layer2 && node >= NS + NE) return;        // k rows unused after layer 2
  const int* rp = rp_all + g*RP;
  const unsigned short* cl = col_all + (size_t)g*NCSR;
  const unsigned short* hgb = layer2 ? hb_base + (size_t)g*NNODE*KD : hb_base;
  const float* ssg = layer2 ? ss + g*NNODE : ss;
  const float* sdg = layer2 ? sd + g*NNODE : sd;
  int e0 = rp[node], e1 = rp[node + 1];
  float sdv = sdg[node];
  int sub = lane >> 4;       // edge subgroup 0..3
  int fl  = lane & 15;       // feature lane: features fl*8 .. fl*8+7
  float l = 0.f;
  float A[8] = {0,0,0,0,0,0,0,0};
  for (int base = e0; base < e1; base += 64) {
    int cnt = e1 - base; if (cnt > 64) cnt = 64;
    if (lane < cnt) colsh[wib][lane] = cl[base + lane];  // coalesced col preload
    int tj = (cnt - sub + 3) >> 2;                       // edges sub+4j, j<tj
    #pragma unroll 2
    for (int j = 0; j < tj; j++) {
      int o = colsh[wib][sub + 4*j];                     // LDS, 1-deep chain
      float pj = __expf(lrelu_(ssg[o] + sdv));
      l += pj;
      short8 mv = *(const short8*)&hgb[(size_t)o*KD + fl*8];   // 16 lanes x 16B = 256B row
      #pragma unroll
      for (int q = 0; q < 8; q++)
        A[q] += pj * bf2f_((unsigned short)mv[q]);
    }
  }
  l += __shfl_xor(l, 16); l += __shfl_xor(l, 32);
  #pragma unroll
  for (int q = 0; q < 8; q++) {
    A[q] += __shfl_xor(A[q], 16);
    A[q] += __shfl_xor(A[q], 32);
  }
  float inv = 1.f/(l + 1e-16f);
  float av[8];
  #pragma unroll
  for (int q = 0; q < 8; q++) av[q] = elu_(A[q]*inv);
  if (!layer2) {
    if (sub == 0) {
      short8 sv;
      #pragma unroll
      for (int q = 0; q < 8; q++) sv[q] = (short)f2b_(av[q]);
      *(short8*)&outb[(size_t)wv*KD + fl*8] = sv;
    }
    return;
  }
  if (g == 0) {
    if (sub == 0) {
      short8 sv;
      #pragma unroll
      for (int q = 0; q < 8; q++) sv[q] = (short)f2b_(av[q]);
      *(short8*)&eoutb[(size_t)node*KD + fl*8] = sv;
    }
  } else {
    float nrm = av[0]*av[0] + av[1]*av[1] + av[2]*av[2] + av[3]*av[3]
              + av[4]*av[4] + av[5]*av[5] + av[6]*av[6] + av[7]*av[7];
    #pragma unroll
    for (int off = 1; off <= 8; off <<= 1) nrm += __shfl_xor(nrm, off);
    float invn = 1.f/(sqrtf(nrm) + 1e-12f);
    if (sub == 0) {
      short8 sv;
      #pragma unroll
      for (int q = 0; q < 8; q++) sv[q] = (short)f2b_(av[q]*invn);
      *(short8*)&Zo[((size_t)(g - 1)*8192 + node)*KD + fl*8] = sv;
    }
  }
}

// ---------- fused: MFMA prediction head (blocks [0,256)) + sim GEMM (rest) ----------
__global__ __launch_bounds__(256)
void k_simhead(const unsigned short* __restrict__ Z, float* __restrict__ rsp,
               float* __restrict__ csp, float* __restrict__ dg_all,
               const unsigned short* __restrict__ pWb,
               const float* __restrict__ pb, const float* __restrict__ knr,
               float* __restrict__ out, const unsigned short* __restrict__ eoutb,
               const int* __restrict__ i1, const int* __restrict__ i2) {
  __shared__ __align__(16) unsigned short U[2*128*KD];   // 64 KB union
  int bid = blockIdx.x, t = threadIdx.x;

  if (bid < BQ/32) {
    // ================= head: 3 chained 32x128x128 bf16 GEMMs =================
    unsigned short* At = U;                 // 8 KB
    unsigned short* Bt = U + 32*KD;         // 8 KB
    unsigned short* Xt = U + 64*KD;         // 8 KB
    float (*nump)[2] = (float(*)[2])(U + 96*KD);
    float (*denp)[2] = (float(*)[2])(U + 96*KD + 128);   // +256 B
    int row0 = bid*32;
    for (int i = t; i < 512; i += 256) {    // 512 8-elem groups per tile
      int r = i >> 4, g = i & 15;
      int sw = g ^ (r & 15);
      *(short8*)&At[(r*16 + sw)*8] =
          *(const short8*)&eoutb[(size_t)i1[row0 + r]*KD + g*8];
      *(short8*)&Bt[(r*16 + sw)*8] =
          *(const short8*)&eoutb[(size_t)(NS + i2[row0 + r])*KD + g*8];
    }
    __syncthreads();
    int w = t >> 6, lane = t & 63;
    int rw = (w >> 1)*16, cw = (w & 1)*64;     // wave -> (16-row, 64-col) quadrant
    int m15 = lane & 15, quad = lane >> 4;
    const unsigned short* W1g = pWb;
    const unsigned short* W2g = pWb + KD*KD;
    const unsigned short* W3g = pWb + 2*KD*KD;
    float4_ accP[4] = {}, accD[4] = {};
    #pragma unroll
    for (int kq = 0; kq < 4; kq++) {
      int g = kq*4 + quad;
      int ra = rw + m15;
      short8 a1 = *(const short8*)&At[(ra*16 + (g ^ (ra & 15)))*8];
      short8 a2 = *(const short8*)&Bt[(ra*16 + (g ^ (ra & 15)))*8];
      #pragma unroll
      for (int ni = 0; ni < 4; ni++) {
        int rb = cw + ni*16 + m15;
        short8 b1 = *(const short8*)&W1g[(size_t)rb*KD + g*8];
        short8 b2 = *(const short8*)&W2g[(size_t)rb*KD + g*8];
        accP[ni] = __builtin_amdgcn_mfma_f32_16x16x32_bf16(a1, b1, accP[ni], 0, 0, 0);
        accD[ni] = __builtin_amdgcn_mfma_f32_16x16x32_bf16(a2, b2, accD[ni], 0, 0, 0);
      }
    }
    #pragma unroll
    for (int ni = 0; ni < 4; ni++) {
      #pragma unroll
      for (int reg = 0; reg < 4; reg++) {
        int lr = rw + quad*4 + reg;
        int col = cw + ni*16 + m15;
        float diff = sigm_(accP[ni][reg]) - sigm_(accD[ni][reg]);
        int g2 = col >> 3;
        Xt[(lr*16 + (g2 ^ (lr & 15)))*8 + (col & 7)] = f2b_(diff);
      }
    }
    __syncthreads();
    float4_ accO[4] = {};
    #pragma unroll
    for (int kq = 0; kq < 4; kq++) {
      int g = kq*4 + quad;
      int ra = rw + m15;
      short8 a = *(const short8*)&Xt[(ra*16 + (g ^ (ra & 15)))*8];
      #pragma unroll
      for (int ni = 0; ni < 4; ni++) {
        int rb = cw + ni*16 + m15;
        short8 b = *(const short8*)&W3g[(size_t)rb*KD + g*8];
        accO[ni] = __builtin_amdgcn_mfma_f32_16x16x32_bf16(a, b, accO[ni], 0, 0, 0);
      }
    }
    float pbv[4];
    #pragma unroll
    for (int ni = 0; ni < 4; ni++) pbv[ni] = pb[cw + ni*16 + m15];
    #pragma unroll
    for (int reg = 0; reg < 4; reg++) {
      int lr = rw + quad*4 + reg;
      int gr = row0 + lr;
      float num = 0.f, den = 0.f;
      #pragma unroll
      for (int ni = 0; ni < 4; ni++) {
        float kr = knr[(size_t)gr*KD + cw + ni*16 + m15];
        float o = sigm_(accO[ni][reg] + pbv[ni]);
        num += o*kr; den += kr;
      }
      num += __shfl_xor(num, 1); den += __shfl_xor(den, 1);
      num += __shfl_xor(num, 2); den += __shfl_xor(den, 2);
      num += __shfl_xor(num, 4); den += __shfl_xor(den, 4);
      num += __shfl_xor(num, 8); den += __shfl_xor(den, 8);
      if (m15 == 0) { nump[lr][w & 1] = num; denp[lr][w & 1] = den; }
    }
    __syncthreads();
    if (t < 32)
      out[row0 + t] = (nump[t][0] + nump[t][1]) / (denp[t][0] + denp[t][1]);
    return;
  }

  // ================= sim: bf16 MFMA similarity GEMM =================
  {
    unsigned short* As = U;
    unsigned short* Bs = U + 128*KD;
    int sb = bid - BQ/32;
    int bx = sb & 31, by = (sb >> 5) & 31, z = sb >> 10;
    const unsigned short* Arow = Z + ((size_t)z*NS + (size_t)bx*128)*KD;
    const unsigned short* Brow = Z + ((size_t)8192 + (size_t)z*NS + (size_t)by*128)*KD;
    #pragma unroll
    for (int j = 0; j < 8; j++) {
      int G = t + j*256;                     // linear 16B-group id, 0..2047
      int r = G >> 4, g = G & 15;
      int sw = g ^ (r & 15);
      *(float4*)&As[(r*16 + sw)*8] = *(const float4*)&Arow[(size_t)G*8];
      *(float4*)&Bs[(r*16 + sw)*8] = *(const float4*)&Brow[(size_t)G*8];
    }
    __syncthreads();
    int w = t >> 6, lane = t & 63;
    int rw = (w >> 1)*64, cw = (w & 1)*64;
    int m15 = lane & 15, quad = lane >> 4;
    float4_ acc[4][4] = {};
    #pragma unroll
    for (int kq = 0; kq < 4; kq++) {
      short8 a[4], b[4];
      int g = kq*4 + quad;
      #pragma unroll
      for (int mi = 0; mi < 4; mi++) {
        int r = rw + mi*16 + m15;
        a[mi] = *(const short8*)&As[(r*16 + (g ^ (r & 15)))*8];
      }
      #pragma unroll
      for (int ni = 0; ni < 4; ni++) {
        int r = cw + ni*16 + m15;
        b[ni] = *(const short8*)&Bs[(r*16 + (g ^ (r & 15)))*8];
      }
      #pragma unroll
      for (int mi = 0; mi < 4; mi++)
        #pragma unroll
        for (int ni = 0; ni < 4; ni++)
          acc[mi][ni] = __builtin_amdgcn_mfma_f32_16x16x32_bf16(a[mi], b[ni], acc[mi][ni], 0, 0, 0);
    }
    int i0 = bx*128, j0 = by*128;
    float* diag = dg_all + z*NS;
    float* rrow = rsp + ((size_t)z*64 + by*2 + (w & 1))*NS;
    float* crow = csp + ((size_t)z*64 + bx*2 + (w >> 1))*NS;
    float cs[4] = {0,0,0,0};
    #pragma unroll
    for (int mi = 0; mi < 4; mi++) {
      float rs[4] = {0,0,0,0};
      #pragma unroll
      for (int ni = 0; ni < 4; ni++) {
        #pragma unroll
        for (int reg = 0; reg < 4; reg++) {
          float sim2 = acc[mi][ni][reg]*2.0f;
          int gi = i0 + rw + mi*16 + quad*4 + reg;     // C/D: row=(lane>>4)*4+reg
          int gj = j0 + cw + ni*16 + m15;              //      col=lane&15
          if (gi == gj) diag[gi] = sim2;
          float e = __expf(sim2);
          rs[reg] += e; cs[ni] += e;
        }
      }
      #pragma unroll
      for (int reg = 0; reg < 4; reg++) {
        float v = rs[reg];
        v += __shfl_xor(v, 1); v += __shfl_xor(v, 2);
        v += __shfl_xor(v, 4); v += __shfl_xor(v, 8);
        if (m15 == 0) rrow[i0 + rw + mi*16 + quad*4 + reg] = v;
      }
    }
    #pragma unroll
    for (int ni = 0; ni < 4; ni++) {
      float v = cs[ni];
      v += __shfl_xor(v, 16); v += __shfl_xor(v, 32);
      if (quad == 0) crow[j0 + cw + ni*16 + m15] = v;
    }
  }
}

// reduce partials -> closs. DETERMINISTIC finalize: slot publish + last-block
// ordered tree reduce (same numerics as the round-2/3 passing path).
__global__ void k_lred(const float* __restrict__ rsp, const float* __restrict__ csp,
                       const float* __restrict__ dg_all, float* __restrict__ out,
                       float* __restrict__ clbuf) {
  __shared__ float red[256];
  __shared__ int lastflag;
  int z = blockIdx.y;
  int i = blockIdx.x*256 + threadIdx.x;
  float rs = 0.f, cs = 0.f;
  for (int s = 0; s < 64; s++) {
    rs += rsp[((size_t)z*64 + s)*NS + i];
    cs += csp[((size_t)z*64 + s)*NS + i];
  }
  float v = logf(rs) + logf(cs) - 2.f*dg_all[z*NS + i];
  red[threadIdx.x] = v; __syncthreads();
  for (int off = 128; off; off >>= 1) {
    if (threadIdx.x < off) red[threadIdx.x] += red[threadIdx.x + off];
    __syncthreads();
  }
  if (threadIdx.x == 0) {
    atomicExch(&clbuf[z*16 + blockIdx.x], red[0]);   // coherent slot publish
    __threadfence();
    int old = atomicAdd((int*)clbuf + 32, 1);
    lastflag = (old == 31) ? 1 : 0;
  }
  __syncthreads();
  if (lastflag && threadIdx.x < 64) {
    int lane = threadIdx.x;
    float pv = (lane < 32) ? atomicAdd(&clbuf[lane], 0.0f) : 0.f;  // atomic load
    #pragma unroll
    for (int off = 32; off; off >>= 1) pv += __shfl_xor(pv, off);
    if (lane == 0) out[BQ] = 0.1f*pv/(float)NS;
  }
}

extern "C" void kernel_launch(void* const* d_in, const int* in_sizes, int n_in,
                              void* d_out, int out_size, void* d_ws, size_t ws_size,
                              hipStream_t stream) {
  const float* E_stu  = (const float*)d_in[0];
  const float* E_exer = (const float*)d_in[1];
  const float* E_k    = (const float*)d_in[2];
  const float* W1  = (const float*)d_in[3];
  const float* a1s = (const float*)d_in[4];
  const float* a1d = (const float*)d_in[5];
  const float* W2  = (const float*)d_in[6];
  const float* a2s = (const float*)d_in[7];
  const float* a2d = (const float*)d_in[8];
  const float* pW1 = (const float*)d_in[9];
  const float* pW2 = (const float*)d_in[10];
  const float* pW3 = (const float*)d_in[11];
  const float* pb3 = (const float*)d_in[12];
  const float* kn_r = (const float*)d_in[13];
  const int* stu_ids  = (const int*)d_in[14];
  const int* exer_ids = (const int*)d_in[15];
  const int* k_ids    = (const int*)d_in[16];
  EdgePtrs ep;
  for (int g = 0; g < 3; g++) {
    ep.s_src[g] = (const int*)d_in[17 + g*4];
    ep.s_dst[g] = (const int*)d_in[18 + g*4];
    ep.e_src[g] = (const int*)d_in[19 + g*4];
    ep.e_dst[g] = (const int*)d_in[20 + g*4];
  }
  const int* stu_index  = (const int*)d_in[29];
  const int* exer_index = (const int*)d_in[30];
  float* out = (float*)d_out;   // [0..8191] predictions, [8192] closs

  // ---- workspace carve ----
  char* p = (char*)d_ws;
  auto carve = [&](size_t bytes) -> char* {
    char* r = p; p += (bytes + 255) & ~(size_t)255; return r;
  };
  const size_t NODE_F = (size_t)NNODE*KD;
  float* ssb = (float*)carve((size_t)8*NNODE*4);
  float* ss0 = ssb,            *sd0 = ssb + NNODE;
  float* ss3 = ssb + 2*NNODE,  *sd3 = ssb + 5*NNODE;
  unsigned short* hb0 = (unsigned short*)carve(NODE_F*2);        // layer-1 h (shared)
  unsigned short* hb3 = (unsigned short*)carve(3*NODE_F*2);      // layer-2 h x3
  // time-multiplexed: CSR partials (6.4 MB) -> layer-1 agg bf16 out (6.4 MB)
  char* Creg = carve((size_t)8*HB*NNODE*4);
  int*   part = (int*)Creg;                       // part[3][HB][NNODE]
  int*   boff = (int*)Creg + (size_t)3*HB*NNODE;  // boff[3][HB][NNODE]
  unsigned short* etb = (unsigned short*)Creg;    // layer-1 agg out, bf16 [3*NNODE][KD]
  unsigned short* eoutb = (unsigned short*)carve((size_t)(NS + NE)*KD*2);  // g0 layer-2 out (bf16)
  int* cnt_all = (int*)carve((size_t)3*NNODE*4);
  int* rp_all  = (int*)carve((size_t)3*RP*4);
  unsigned short* col_all = (unsigned short*)carve((size_t)3*NCSR*2);
  unsigned short* pWb = (unsigned short*)carve((size_t)3*KD*KD*2);  // bf16 head W x3
  float* rsp = (float*)carve((size_t)2*64*NS*4);   // rowsum partials
  float* csp = (float*)carve((size_t)2*64*NS*4);   // colsum partials
  float* dg_all = (float*)carve((size_t)2*NS*4);
  float* clbuf = (float*)carve(256);               // [0..31] partials, [32] counter
  unsigned short* Z = (unsigned short*)carve((size_t)2*8192*KD*2);  // bf16 Z1|Z2
  unsigned short* w2b = (unsigned short*)carve((size_t)KD*KD*2);    // bf16 W2^T [c][k]

  // ---- fused: CSR hist ∪ layer-1 fp32 GEMM (8-row blocks) ∪ weight converts ----
  k_fuse1<<<3*HB + NNODE/8 + 16 + 12, 256, 0, stream>>>(
      ep, part, W1, a1s, a1d, hb0, ss0, sd0,
      E_stu, E_exer, E_k, stu_ids, exer_ids, k_ids,
      pW1, pW2, pW3, pWb, W2, w2b);

  // ---- CSR scan chain (3 small kernels; machine-wide parallel) ----
  k_sumpart<<<(3*NNODE + 255)/256, 256, 0, stream>>>(part, cnt_all);
  k_scan<<<3, 1024, 0, stream>>>(cnt_all, rp_all);
  k_boff<<<(3*NNODE + 255)/256, 256, 0, stream>>>(part, rp_all, boff, clbuf);
  k_scatter<<<dim3(HB, 3), 256, 0, stream>>>(ep, boff, col_all);

  // ---- GAT layer 1 aggregation (batched) ----
  k_agg<<<3*NNODE/4, 256, 0, stream>>>(rp_all, col_all, hb0, ss0, sd0, etb,
                                       nullptr, nullptr, -1);

  // ---- GAT layer 2 (bf16 MFMA node GEMM; batched agg) ----
  k_mgemm<<<3*NNODE/128, 256, 0, stream>>>(etb, w2b, a2s, a2d, hb3, ss3, sd3);
  k_agg<<<3*NNODE/4, 256, 0, stream>>>(rp_all, col_all, hb3, ss3, sd3, nullptr,
                                       eoutb, Z, -2);

  // ---- fused: prediction head (256 blocks) ∥ sim GEMM (2048 blocks) ----
  k_simhead<<<BQ/32 + 2048, 256, 0, stream>>>(Z, rsp, csp, dg_all,
                                              pWb, pb3, kn_r, out, eoutb,
                                              stu_index, exer_index);

  // ---- closs reduce + deterministic last-block finalize ----
  k_lred<<<dim3(16, 2), 256, 0, stream>>>(rsp, csp, dg_all, out, clbuf);
}

// Round 14
// 258.088 us; speedup vs baseline: 1.2207x; 1.0196x over previous
//
#include <hip/hip_runtime.h>
#include <hip/hip_bf16.h>
#include <math.h>

#define KD 128
#define NS 4096
#define NE 4096
#define NK 128
#define NNODE (NS + NE + NK)      // 8320
#define ESE 131072
#define EEK 16384
#define NCSR (2*ESE + 2*EEK)      // 294912
#define BQ 8192
#define RP (NNODE + 1)
#define HB 64                     // CSR-build blocks per graph (round-13: 32 -> 64
                                  // so scatter's grid covers 192/256 CUs, not 96)

typedef __attribute__((ext_vector_type(8))) short short8;   // 8 bf16 (4 VGPRs)
typedef __attribute__((ext_vector_type(4))) short short4_;  // 4 bf16 (8B)
typedef __attribute__((ext_vector_type(4))) float float4_;  // 4 fp32 acc

__device__ __forceinline__ float lrelu_(float x){ return x >= 0.f ? x : 0.2f*x; }
__device__ __forceinline__ float elu_(float x){ return x > 0.f ? x : __expf(x) - 1.f; }
__device__ __forceinline__ float sigm_(float x){ return 1.f/(1.f + __expf(-x)); }
__device__ __forceinline__ float bf2f_(unsigned short u){
  union { unsigned int i; float f; } v; v.i = ((unsigned int)u) << 16; return v.f;
}
__device__ __forceinline__ unsigned short f2b_(float x){
  __hip_bfloat16 b = __float2bfloat16(x); return *(unsigned short*)&b;
}

struct EdgePtrs { const int* s_src[3]; const int* s_dst[3]; const int* e_src[3]; const int* e_dst[3]; };

// ================= fused independent-phase kernel =================
// blocks [0,192):      CSR histogram (LDS, no global atomics)     -> part
// blocks [192,1232):   layer-1 node GEMM fp32, 8 rows/block       -> hb0/ss0/sd0
// blocks [1232,1248):  W2 transpose -> bf16 (MFMA B-operand)      -> w2b
// blocks [1248,1260):  head weights -> bf16 copy                  -> pWb
// NOTE: layer-1 stays fp32-VALU (round-5/6 lesson: closs tolerance).
// CSR build stays LDS-cursor based (round-8/9: global atomic cursors ping-pong
// across non-coherent XCD L2s). CSR mid-chain stays 3 kernels (round-12: a
// 3-block merged kernel is single-CU-BW-bound at 68 us).
__global__ __launch_bounds__(256)
void k_fuse1(EdgePtrs ep, int* __restrict__ part,
             const float* __restrict__ W1, const float* __restrict__ a1s,
             const float* __restrict__ a1d,
             unsigned short* __restrict__ hb0, float* __restrict__ ss0,
             float* __restrict__ sd0,
             const float* __restrict__ E_stu, const float* __restrict__ E_exer,
             const float* __restrict__ E_k, const int* __restrict__ sid,
             const int* __restrict__ eid, const int* __restrict__ kid,
             const float* __restrict__ pW1, const float* __restrict__ pW2,
             const float* __restrict__ pW3, unsigned short* __restrict__ pWb,
             const float* __restrict__ W2, unsigned short* __restrict__ w2b) {
  __shared__ __align__(16) char smem[NNODE*4];   // 33 KB union
  int bid = blockIdx.x, t = threadIdx.x;

  if (bid < 3*HB) {
    // ---- CSR histogram ----
    int* hcnt = (int*)smem;
    int g = bid / HB, b = bid % HB;
    for (int i = t; i < NNODE; i += 256) hcnt[i] = 0;
    __syncthreads();
    const int* ss_ = ep.s_src[g]; const int* sd_ = ep.s_dst[g];
    const int* es_ = ep.e_src[g]; const int* ed_ = ep.e_dst[g];
    int se0 = b*(ESE/HB);
    for (int i = se0 + t; i < se0 + ESE/HB; i += 256) {
      atomicAdd(&hcnt[ss_[i]], 1);
      atomicAdd(&hcnt[NS + sd_[i]], 1);
    }
    int ek0 = b*(EEK/HB);
    for (int i = ek0 + t; i < ek0 + EEK/HB; i += 256) {
      atomicAdd(&hcnt[NS + es_[i]], 1);
      atomicAdd(&hcnt[NS + NE + ed_[i]], 1);
    }
    __syncthreads();
    int* pp = part + ((size_t)g*HB + b)*NNODE;
    for (int i = t; i < NNODE; i += 256) pp[i] = hcnt[i];
    return;
  }

  if (bid < 3*HB + NNODE/8) {
    // ---- layer-1 node GEMM (fp32 VALU, 8 rows/block for 16 waves/CU) ----
    float (*ers)[KD] = (float(*)[KD])smem;       // 4 KB of the union
    int row0 = (bid - 3*HB)*8;
    int w = t >> 6, c = t & 63;
    for (int i = t; i < 8*KD; i += 256) {
      int r = i >> 7, k = i & 127;
      int gr = row0 + r;
      const float* srow;
      if (gr < NS)           srow = E_stu  + (size_t)sid[gr]*KD;
      else if (gr < NS + NE) srow = E_exer + (size_t)eid[gr - NS]*KD;
      else                   srow = E_k    + (size_t)kid[gr - NS - NE]*KD;
      ers[r][k] = srow[k];
    }
    __syncthreads();
    float acc0[2] = {0,0}, acc1[2] = {0,0};
    #pragma unroll 2
    for (int kc = 0; kc < KD; kc += 4) {
      float wa[4], wb[4];
      #pragma unroll
      for (int j = 0; j < 4; j++) {
        wa[j] = W1[(kc + j)*KD + c];
        wb[j] = W1[(kc + j)*KD + c + 64];
      }
      #pragma unroll
      for (int r = 0; r < 2; r++) {
        float4 e = *(const float4*)&ers[w*2 + r][kc];
        acc0[r] += e.x*wa[0] + e.y*wa[1] + e.z*wa[2] + e.w*wa[3];
        acc1[r] += e.x*wb[0] + e.y*wb[1] + e.z*wb[2] + e.w*wb[3];
      }
    }
    float as1 = a1s[c], as2 = a1s[c + 64], ad1 = a1d[c], ad2 = a1d[c + 64];
    #pragma unroll
    for (int r = 0; r < 2; r++) {
      int gr = row0 + w*2 + r;
      hb0[(size_t)gr*KD + c]      = f2b_(acc0[r]);
      hb0[(size_t)gr*KD + c + 64] = f2b_(acc1[r]);
      float s = acc0[r]*as1 + acc1[r]*as2;
      float d = acc0[r]*ad1 + acc1[r]*ad2;
      #pragma unroll
      for (int off = 32; off; off >>= 1) { s += __shfl_xor(s, off); d += __shfl_xor(d, off); }
      if (c == 0) { ss0[gr] = s; sd0[gr] = d; }
    }
    return;
  }

  {
    int idx = bid - 3*HB - NNODE/8;              // 0..27
    if (idx < 16) {
      // ---- W2 transpose -> bf16 table w2b[c][k] = bf16(W2[k][c]) ----
      float (*tile)[33] = (float(*)[33])smem;
      int tx = t & 31, ty = t >> 5;              // (32,8) mapping
      int bx = (idx & 3)*32, by = (idx >> 2)*32;
      for (int j = 0; j < 32; j += 8)
        tile[ty + j][tx] = W2[(by + ty + j)*KD + bx + tx];
      __syncthreads();
      for (int j = 0; j < 32; j += 8)
        w2b[(bx + ty + j)*KD + by + tx] = f2b_(tile[tx][ty + j]);
    } else {
      // ---- head weights -> bf16 copy (no transpose: B-operand row = W row) ----
      int r = idx - 16;                          // 0..11, 4 blocks per matrix
      const float* src = r < 4 ? pW1 : (r < 8 ? pW2 : pW3);
      unsigned short* dst = pWb + (size_t)(r >> 2)*KD*KD;
      int off = (r & 3)*4096;
      for (int i = t; i < 1024; i += 256) {
        float4 v = *(const float4*)&src[off + i*4];
        short4_ s;
        s[0] = (short)f2b_(v.x); s[1] = (short)f2b_(v.y);
        s[2] = (short)f2b_(v.z); s[3] = (short)f2b_(v.w);
        *(short4_*)&dst[off + i*4] = s;
      }
    }
  }
}

// thread-per-node partial-sum: cnt[g][n] = sum_b part[g][b][n]  (coalesced over n)
__global__ void k_sumpart(const int* __restrict__ part, int* __restrict__ cnt_all) {
  int idx = blockIdx.x*256 + threadIdx.x;
  if (idx >= 3*NNODE) return;
  int g = idx / NNODE, n = idx - g*NNODE;
  const int* pg = part + (size_t)g*HB*NNODE + n;
  int s = 0;
  #pragma unroll
  for (int b = 0; b < HB; b++) s += pg[(size_t)b*NNODE];
  cnt_all[idx] = s;
}

// per-graph single-block scan of cnt -> row_ptr
__global__ void k_scan(const int* __restrict__ cnt_all, int* __restrict__ rp_all) {
  __shared__ int sums[1024];
  const int CH = (NNODE + 1023) / 1024;    // 9
  int g = blockIdx.x, t = threadIdx.x;
  const int* cnt = cnt_all + g*NNODE;
  int* row_ptr = rp_all + g*RP;
  int base = t*CH;
  int local[CH];
  int s = 0;
  for (int j = 0; j < CH; j++) {
    int v = (base + j < NNODE) ? cnt[base + j] : 0;
    local[j] = s; s += v;
  }
  sums[t] = s; __syncthreads();
  for (int off = 1; off < 1024; off <<= 1) {
    int v = (t >= off) ? sums[t - off] : 0;
    __syncthreads();
    sums[t] += v;
    __syncthreads();
  }
  int excl = (t == 0) ? 0 : sums[t - 1];
  for (int j = 0; j < CH; j++)
    if (base + j < NNODE) row_ptr[base + j] = excl + local[j];
  if (t == 1023) row_ptr[NNODE] = sums[1023];
}

// thread-per-node: emit per-block cursors boff[g][b][n]; idx 0 zeroes closs counter
__global__ void k_boff(const int* __restrict__ part, const int* __restrict__ rp_all,
                       int* __restrict__ boff, float* __restrict__ clbuf) {
  int idx = blockIdx.x*256 + threadIdx.x;
  if (idx == 0) ((int*)clbuf)[32] = 0;     // counter; slots [0..31] written by exch
  if (idx >= 3*NNODE) return;
  int g = idx / NNODE, n = idx - g*NNODE;
  const int* pg = part + (size_t)g*HB*NNODE + n;
  int* bg = boff + (size_t)g*HB*NNODE + n;
  int acc = rp_all[g*RP + n];
  #pragma unroll
  for (int b = 0; b < HB; b++) {
    bg[(size_t)b*NNODE] = acc;
    acc += pg[(size_t)b*NNODE];
  }
}

// scatter via LDS cursors initialized from boff (no global atomics); col stored ushort
__global__ __launch_bounds__(256)
void k_scatter(EdgePtrs ep, const int* __restrict__ boff, unsigned short* __restrict__ col_all) {
  __shared__ int cur[NNODE];      // 33 KB live cursors
  int g = blockIdx.y, b = blockIdx.x, t = threadIdx.x;
  const int* bg = boff + ((size_t)g*HB + b)*NNODE;
  for (int i = t; i < NNODE; i += 256) cur[i] = bg[i];
  __syncthreads();
  const int* ss_ = ep.s_src[g]; const int* sd_ = ep.s_dst[g];
  const int* es_ = ep.e_src[g]; const int* ed_ = ep.e_dst[g];
  unsigned short* col = col_all + (size_t)g*NCSR;
  int se0 = b*(ESE/HB);
  for (int i = se0 + t; i < se0 + ESE/HB; i += 256) {
    int s = ss_[i], d = NS + sd_[i];
    col[atomicAdd(&cur[s], 1)] = (unsigned short)d;
    col[atomicAdd(&cur[d], 1)] = (unsigned short)s;
  }
  int ek0 = b*(EEK/HB);
  for (int i = ek0 + t; i < ek0 + EEK/HB; i += 256) {
    int s = NS + es_[i], d = NS + NE + ed_[i];
    col[atomicAdd(&cur[s], 1)] = (unsigned short)d;
    col[atomicAdd(&cur[d], 1)] = (unsigned short)s;
  }
}

// ---------- layer-2 node GEMM on MFMA (bf16 x, bf16 W2^T, fp32 acc) ----------
__global__ __launch_bounds__(256)
void k_mgemm(const unsigned short* __restrict__ X, const unsigned short* __restrict__ WT,
             const float* __restrict__ a_s, const float* __restrict__ a_d,
             unsigned short* __restrict__ hb, float* __restrict__ ss,
             float* __restrict__ sd) {
  __shared__ unsigned short As[128*KD];   // 32 KB, swizzled: row r, group g at (g ^ (r&15))
  __shared__ unsigned short Bs[128*KD];   // 32 KB (W2^T rows)
  __shared__ float ssp[128][2], sdp[128][2];
  int t = threadIdx.x;
  const unsigned short* Arow = X + (size_t)blockIdx.x*128*KD;
  #pragma unroll
  for (int j = 0; j < 8; j++) {
    int G = t + j*256;                     // linear 16B-group id, 0..2047
    int r = G >> 4, g = G & 15;
    int sw = g ^ (r & 15);
    *(float4*)&As[(r*16 + sw)*8] = *(const float4*)&Arow[(size_t)G*8];
    *(float4*)&Bs[(r*16 + sw)*8] = *(const float4*)&WT[(size_t)G*8];
  }
  __syncthreads();
  int w = t >> 6, lane = t & 63;
  int rw = (w >> 1)*64, cw = (w & 1)*64;
  int m15 = lane & 15, quad = lane >> 4;
  float4_ acc[4][4] = {};
  #pragma unroll
  for (int kq = 0; kq < 4; kq++) {
    short8 a[4], b[4];
    int g = kq*4 + quad;
    #pragma unroll
    for (int mi = 0; mi < 4; mi++) {
      int r = rw + mi*16 + m15;
      a[mi] = *(const short8*)&As[(r*16 + (g ^ (r & 15)))*8];
    }
    #pragma unroll
    for (int ni = 0; ni < 4; ni++) {
      int r = cw + ni*16 + m15;
      b[ni] = *(const short8*)&Bs[(r*16 + (g ^ (r & 15)))*8];
    }
    #pragma unroll
    for (int mi = 0; mi < 4; mi++)
      #pragma unroll
      for (int ni = 0; ni < 4; ni++)
        acc[mi][ni] = __builtin_amdgcn_mfma_f32_16x16x32_bf16(a[mi], b[ni], acc[mi][ni], 0, 0, 0);
  }
  int row0 = blockIdx.x*128;
  float asv[4], adv[4];
  #pragma unroll
  for (int ni = 0; ni < 4; ni++) {
    int gc = cw + ni*16 + m15;
    asv[ni] = a_s[gc]; adv[ni] = a_d[gc];
  }
  #pragma unroll
  for (int mi = 0; mi < 4; mi++) {
    #pragma unroll
    for (int reg = 0; reg < 4; reg++) {
      int lr = rw + mi*16 + quad*4 + reg;          // C/D: row=(lane>>4)*4+reg
      int gr = row0 + lr;
      float s = 0.f, d = 0.f;
      #pragma unroll
      for (int ni = 0; ni < 4; ni++) {
        float v = acc[mi][ni][reg];
        hb[(size_t)gr*KD + cw + ni*16 + m15] = f2b_(v);   // col=lane&15
        s += v*asv[ni]; d += v*adv[ni];
      }
      s += __shfl_xor(s, 1); d += __shfl_xor(d, 1);
      s += __shfl_xor(s, 2); d += __shfl_xor(d, 2);
      s += __shfl_xor(s, 4); d += __shfl_xor(d, 4);
      s += __shfl_xor(s, 8); d += __shfl_xor(d, 8);
      if (m15 == 0) { ssp[lr][w & 1] = s; sdp[lr][w & 1] = d; }
    }
  }
  __syncthreads();
  if (t < 128) {
    ss[row0 + t] = ssp[t][0] + ssp[t][1];
    sd[row0 + t] = sdp[t][0] + sdp[t][1];
  }
}

// ---------- segment-softmax aggregation, LDS col-staged (1-deep chain) ----------
// Wave stages its next 64 cols in a PRIVATE LDS strip (no cross-lane ops);
// subgroup edge order (e = base+sub+4j, ascending) IDENTICAL to the proven
// strided loop. unroll 2: more loads in flight; statement order preserved.
__global__ __launch_bounds__(256)
void k_agg(const int* __restrict__ rp_all, const unsigned short* __restrict__ col_all,
           const unsigned short* __restrict__ hb_base, const float* __restrict__ ss,
           const float* __restrict__ sd, unsigned short* __restrict__ outb,
           unsigned short* __restrict__ eoutb, unsigned short* __restrict__ Zo, int gsel) {
  __shared__ unsigned short colsh[4][64];   // per-wave private strip
  int wib = threadIdx.x >> 6;
  int wv = blockIdx.x*4 + wib;
  int lane = threadIdx.x & 63;
  if (wv >= 3*NNODE) return;
  int g = wv / NNODE, node = wv - g*NNODE;
  bool layer2 = (gsel == -2);
  if (layer2 && node >= NS + NE) return;        // k rows unused after layer 2
  const int* rp = rp_all + g*RP;
  const unsigned short* cl = col_all + (size_t)g*NCSR;
  const unsigned short* hgb = layer2 ? hb_base + (size_t)g*NNODE*KD : hb_base;
  const float* ssg = layer2 ? ss + g*NNODE : ss;
  const float* sdg = layer2 ? sd + g*NNODE : sd;
  int e0 = rp[node], e1 = rp[node + 1];
  float sdv = sdg[node];
  int sub = lane >> 4;       // edge subgroup 0..3
  int fl  = lane & 15;       // feature lane: features fl*8 .. fl*8+7
  float l = 0.f;
  float A[8] = {0,0,0,0,0,0,0,0};
  for (int base = e0; base < e1; base += 64) {
    int cnt = e1 - base; if (cnt > 64) cnt = 64;
    if (lane < cnt) colsh[wib][lane] = cl[base + lane];  // coalesced col preload
    int tj = (cnt - sub + 3) >> 2;                       // edges sub+4j, j<tj
    #pragma unroll 2
    for (int j = 0; j < tj; j++) {
      int o = colsh[wib][sub + 4*j];                     // LDS, 1-deep chain
      float pj = __expf(lrelu_(ssg[o] + sdv));
      l += pj;
      short8 mv = *(const short8*)&hgb[(size_t)o*KD + fl*8];   // 16 lanes x 16B = 256B row
      #pragma unroll
      for (int q = 0; q < 8; q++)
        A[q] += pj * bf2f_((unsigned short)mv[q]);
    }
  }
  l += __shfl_xor(l, 16); l += __shfl_xor(l, 32);
  #pragma unroll
  for (int q = 0; q < 8; q++) {
    A[q] += __shfl_xor(A[q], 16);
    A[q] += __shfl_xor(A[q], 32);
  }
  float inv = 1.f/(l + 1e-16f);
  float av[8];
  #pragma unroll
  for (int q = 0; q < 8; q++) av[q] = elu_(A[q]*inv);
  if (!layer2) {
    if (sub == 0) {
      short8 sv;
      #pragma unroll
      for (int q = 0; q < 8; q++) sv[q] = (short)f2b_(av[q]);
      *(short8*)&outb[(size_t)wv*KD + fl*8] = sv;
    }
    return;
  }
  if (g == 0) {
    if (sub == 0) {
      short8 sv;
      #pragma unroll
      for (int q = 0; q < 8; q++) sv[q] = (short)f2b_(av[q]);
      *(short8*)&eoutb[(size_t)node*KD + fl*8] = sv;
    }
  } else {
    float nrm = av[0]*av[0] + av[1]*av[1] + av[2]*av[2] + av[3]*av[3]
              + av[4]*av[4] + av[5]*av[5] + av[6]*av[6] + av[7]*av[7];
    #pragma unroll
    for (int off = 1; off <= 8; off <<= 1) nrm += __shfl_xor(nrm, off);
    float invn = 1.f/(sqrtf(nrm) + 1e-12f);
    if (sub == 0) {
      short8 sv;
      #pragma unroll
      for (int q = 0; q < 8; q++) sv[q] = (short)f2b_(av[q]*invn);
      *(short8*)&Zo[((size_t)(g - 1)*8192 + node)*KD + fl*8] = sv;
    }
  }
}

// ---------- fused: MFMA prediction head (blocks [0,256)) + sim GEMM (rest) ----------
__global__ __launch_bounds__(256)
void k_simhead(const unsigned short* __restrict__ Z, float* __restrict__ rsp,
               float* __restrict__ csp, float* __restrict__ dg_all,
               const unsigned short* __restrict__ pWb,
               const float* __restrict__ pb, const float* __restrict__ knr,
               float* __restrict__ out, const unsigned short* __restrict__ eoutb,
               const int* __restrict__ i1, const int* __restrict__ i2) {
  __shared__ __align__(16) unsigned short U[2*128*KD];   // 64 KB union
  int bid = blockIdx.x, t = threadIdx.x;

  if (bid < BQ/32) {
    // ================= head: 3 chained 32x128x128 bf16 GEMMs =================
    unsigned short* At = U;                 // 8 KB
    unsigned short* Bt = U + 32*KD;         // 8 KB
    unsigned short* Xt = U + 64*KD;         // 8 KB
    float (*nump)[2] = (float(*)[2])(U + 96*KD);
    float (*denp)[2] = (float(*)[2])(U + 96*KD + 128);   // +256 B
    int row0 = bid*32;
    for (int i = t; i < 512; i += 256) {    // 512 8-elem groups per tile
      int r = i >> 4, g = i & 15;
      int sw = g ^ (r & 15);
      *(short8*)&At[(r*16 + sw)*8] =
          *(const short8*)&eoutb[(size_t)i1[row0 + r]*KD + g*8];
      *(short8*)&Bt[(r*16 + sw)*8] =
          *(const short8*)&eoutb[(size_t)(NS + i2[row0 + r])*KD + g*8];
    }
    __syncthreads();
    int w = t >> 6, lane = t & 63;
    int rw = (w >> 1)*16, cw = (w & 1)*64;     // wave -> (16-row, 64-col) quadrant
    int m15 = lane & 15, quad = lane >> 4;
    const unsigned short* W1g = pWb;
    const unsigned short* W2g = pWb + KD*KD;
    const unsigned short* W3g = pWb + 2*KD*KD;
    float4_ accP[4] = {}, accD[4] = {};
    #pragma unroll
    for (int kq = 0; kq < 4; kq++) {
      int g = kq*4 + quad;
      int ra = rw + m15;
      short8 a1 = *(const short8*)&At[(ra*16 + (g ^ (ra & 15)))*8];
      short8 a2 = *(const short8*)&Bt[(ra*16 + (g ^ (ra & 15)))*8];
      #pragma unroll
      for (int ni = 0; ni < 4; ni++) {
        int rb = cw + ni*16 + m15;
        short8 b1 = *(const short8*)&W1g[(size_t)rb*KD + g*8];
        short8 b2 = *(const short8*)&W2g[(size_t)rb*KD + g*8];
        accP[ni] = __builtin_amdgcn_mfma_f32_16x16x32_bf16(a1, b1, accP[ni], 0, 0, 0);
        accD[ni] = __builtin_amdgcn_mfma_f32_16x16x32_bf16(a2, b2, accD[ni], 0, 0, 0);
      }
    }
    #pragma unroll
    for (int ni = 0; ni < 4; ni++) {
      #pragma unroll
      for (int reg = 0; reg < 4; reg++) {
        int lr = rw + quad*4 + reg;
        int col = cw + ni*16 + m15;
        float diff = sigm_(accP[ni][reg]) - sigm_(accD[ni][reg]);
        int g2 = col >> 3;
        Xt[(lr*16 + (g2 ^ (lr & 15)))*8 + (col & 7)] = f2b_(diff);
      }
    }
    __syncthreads();
    float4_ accO[4] = {};
    #pragma unroll
    for (int kq = 0; kq < 4; kq++) {
      int g = kq*4 + quad;
      int ra = rw + m15;
      short8 a = *(const short8*)&Xt[(ra*16 + (g ^ (ra & 15)))*8];
      #pragma unroll
      for (int ni = 0; ni < 4; ni++) {
        int rb = cw + ni*16 + m15;
        short8 b = *(const short8*)&W3g[(size_t)rb*KD + g*8];
        accO[ni] = __builtin_amdgcn_mfma_f32_16x16x32_bf16(a, b, accO[ni], 0, 0, 0);
      }
    }
    float pbv[4];
    #pragma unroll
    for (int ni = 0; ni < 4; ni++) pbv[ni] = pb[cw + ni*16 + m15];
    #pragma unroll
    for (int reg = 0; reg < 4; reg++) {
      int lr = rw + quad*4 + reg;
      int gr = row0 + lr;
      float num = 0.f, den = 0.f;
      #pragma unroll
      for (int ni = 0; ni < 4; ni++) {
        float kr = knr[(size_t)gr*KD + cw + ni*16 + m15];
        float o = sigm_(accO[ni][reg] + pbv[ni]);
        num += o*kr; den += kr;
      }
      num += __shfl_xor(num, 1); den += __shfl_xor(den, 1);
      num += __shfl_xor(num, 2); den += __shfl_xor(den, 2);
      num += __shfl_xor(num, 4); den += __shfl_xor(den, 4);
      num += __shfl_xor(num, 8); den += __shfl_xor(den, 8);
      if (m15 == 0) { nump[lr][w & 1] = num; denp[lr][w & 1] = den; }
    }
    __syncthreads();
    if (t < 32)
      out[row0 + t] = (nump[t][0] + nump[t][1]) / (denp[t][0] + denp[t][1]);
    return;
  }

  // ================= sim: bf16 MFMA similarity GEMM =================
  {
    unsigned short* As = U;
    unsigned short* Bs = U + 128*KD;
    int sb = bid - BQ/32;
    int bx = sb & 31, by = (sb >> 5) & 31, z = sb >> 10;
    const unsigned short* Arow = Z + ((size_t)z*NS + (size_t)bx*128)*KD;
    const unsigned short* Brow = Z + ((size_t)8192 + (size_t)z*NS + (size_t)by*128)*KD;
    #pragma unroll
    for (int j = 0; j < 8; j++) {
      int G = t + j*256;                     // linear 16B-group id, 0..2047
      int r = G >> 4, g = G & 15;
      int sw = g ^ (r & 15);
      *(float4*)&As[(r*16 + sw)*8] = *(const float4*)&Arow[(size_t)G*8];
      *(float4*)&Bs[(r*16 + sw)*8] = *(const float4*)&Brow[(size_t)G*8];
    }
    __syncthreads();
    int w = t >> 6, lane = t & 63;
    int rw = (w >> 1)*64, cw = (w & 1)*64;
    int m15 = lane & 15, quad = lane >> 4;
    float4_ acc[4][4] = {};
    #pragma unroll
    for (int kq = 0; kq < 4; kq++) {
      short8 a[4], b[4];
      int g = kq*4 + quad;
      #pragma unroll
      for (int mi = 0; mi < 4; mi++) {
        int r = rw + mi*16 + m15;
        a[mi] = *(const short8*)&As[(r*16 + (g ^ (r & 15)))*8];
      }
      #pragma unroll
      for (int ni = 0; ni < 4; ni++) {
        int r = cw + ni*16 + m15;
        b[ni] = *(const short8*)&Bs[(r*16 + (g ^ (r & 15)))*8];
      }
      #pragma unroll
      for (int mi = 0; mi < 4; mi++)
        #pragma unroll
        for (int ni = 0; ni < 4; ni++)
          acc[mi][ni] = __builtin_amdgcn_mfma_f32_16x16x32_bf16(a[mi], b[ni], acc[mi][ni], 0, 0, 0);
    }
    int i0 = bx*128, j0 = by*128;
    float* diag = dg_all + z*NS;
    float* rrow = rsp + ((size_t)z*64 + by*2 + (w & 1))*NS;
    float* crow = csp + ((size_t)z*64 + bx*2 + (w >> 1))*NS;
    float cs[4] = {0,0,0,0};
    #pragma unroll
    for (int mi = 0; mi < 4; mi++) {
      float rs[4] = {0,0,0,0};
      #pragma unroll
      for (int ni = 0; ni < 4; ni++) {
        #pragma unroll
        for (int reg = 0; reg < 4; reg++) {
          float sim2 = acc[mi][ni][reg]*2.0f;
          int gi = i0 + rw + mi*16 + quad*4 + reg;     // C/D: row=(lane>>4)*4+reg
          int gj = j0 + cw + ni*16 + m15;              //      col=lane&15
          if (gi == gj) diag[gi] = sim2;
          float e = __expf(sim2);
          rs[reg] += e; cs[ni] += e;
        }
      }
      #pragma unroll
      for (int reg = 0; reg < 4; reg++) {
        float v = rs[reg];
        v += __shfl_xor(v, 1); v += __shfl_xor(v, 2);
        v += __shfl_xor(v, 4); v += __shfl_xor(v, 8);
        if (m15 == 0) rrow[i0 + rw + mi*16 + quad*4 + reg] = v;
      }
    }
    #pragma unroll
    for (int ni = 0; ni < 4; ni++) {
      float v = cs[ni];
      v += __shfl_xor(v, 16); v += __shfl_xor(v, 32);
      if (quad == 0) crow[j0 + cw + ni*16 + m15] = v;
    }
  }
}

// reduce partials -> closs. DETERMINISTIC finalize: slot publish + last-block
// ordered tree reduce (same numerics as the round-2/3 passing path).
__global__ void k_lred(const float* __restrict__ rsp, const float* __restrict__ csp,
                       const float* __restrict__ dg_all, float* __restrict__ out,
                       float* __restrict__ clbuf) {
  __shared__ float red[256];
  __shared__ int lastflag;
  int z = blockIdx.y;
  int i = blockIdx.x*256 + threadIdx.x;
  float rs = 0.f, cs = 0.f;
  for (int s = 0; s < 64; s++) {
    rs += rsp[((size_t)z*64 + s)*NS + i];
    cs += csp[((size_t)z*64 + s)*NS + i];
  }
  float v = logf(rs) + logf(cs) - 2.f*dg_all[z*NS + i];
  red[threadIdx.x] = v; __syncthreads();
  for (int off = 128; off; off >>= 1) {
    if (threadIdx.x < off) red[threadIdx.x] += red[threadIdx.x + off];
    __syncthreads();
  }
  if (threadIdx.x == 0) {
    atomicExch(&clbuf[z*16 + blockIdx.x], red[0]);   // coherent slot publish
    __threadfence();
    int old = atomicAdd((int*)clbuf + 32, 1);
    lastflag = (old == 31) ? 1 : 0;
  }
  __syncthreads();
  if (lastflag && threadIdx.x < 64) {
    int lane = threadIdx.x;
    float pv = (lane < 32) ? atomicAdd(&clbuf[lane], 0.0f) : 0.f;  // atomic load
    #pragma unroll
    for (int off = 32; off; off >>= 1) pv += __shfl_xor(pv, off);
    if (lane == 0) out[BQ] = 0.1f*pv/(float)NS;
  }
}

extern "C" void kernel_launch(void* const* d_in, const int* in_sizes, int n_in,
                              void* d_out, int out_size, void* d_ws, size_t ws_size,
                              hipStream_t stream) {
  const float* E_stu  = (const float*)d_in[0];
  const float* E_exer = (const float*)d_in[1];
  const float* E_k    = (const float*)d_in[2];
  const float* W1  = (const float*)d_in[3];
  const float* a1s = (const float*)d_in[4];
  const float* a1d = (const float*)d_in[5];
  const float* W2  = (const float*)d_in[6];
  const float* a2s = (const float*)d_in[7];
  const float* a2d = (const float*)d_in[8];
  const float* pW1 = (const float*)d_in[9];
  const float* pW2 = (const float*)d_in[10];
  const float* pW3 = (const float*)d_in[11];
  const float* pb3 = (const float*)d_in[12];
  const float* kn_r = (const float*)d_in[13];
  const int* stu_ids  = (const int*)d_in[14];
  const int* exer_ids = (const int*)d_in[15];
  const int* k_ids    = (const int*)d_in[16];
  EdgePtrs ep;
  for (int g = 0; g < 3; g++) {
    ep.s_src[g] = (const int*)d_in[17 + g*4];
    ep.s_dst[g] = (const int*)d_in[18 + g*4];
    ep.e_src[g] = (const int*)d_in[19 + g*4];
    ep.e_dst[g] = (const int*)d_in[20 + g*4];
  }
  const int* stu_index  = (const int*)d_in[29];
  const int* exer_index = (const int*)d_in[30];
  float* out = (float*)d_out;   // [0..8191] predictions, [8192] closs

  // ---- workspace carve ----
  char* p = (char*)d_ws;
  auto carve = [&](size_t bytes) -> char* {
    char* r = p; p += (bytes + 255) & ~(size_t)255; return r;
  };
  const size_t NODE_F = (size_t)NNODE*KD;
  float* ssb = (float*)carve((size_t)8*NNODE*4);
  float* ss0 = ssb,            *sd0 = ssb + NNODE;
  float* ss3 = ssb + 2*NNODE,  *sd3 = ssb + 5*NNODE;
  unsigned short* hb0 = (unsigned short*)carve(NODE_F*2);        // layer-1 h (shared)
  unsigned short* hb3 = (unsigned short*)carve(3*NODE_F*2);      // layer-2 h x3
  // time-multiplexed: CSR partials (12.8 MB at HB=64) -> layer-1 agg bf16 out
  char* Creg = carve((size_t)8*HB*NNODE*4);
  int*   part = (int*)Creg;                       // part[3][HB][NNODE]
  int*   boff = (int*)Creg + (size_t)3*HB*NNODE;  // boff[3][HB][NNODE]
  unsigned short* etb = (unsigned short*)Creg;    // layer-1 agg out, bf16 [3*NNODE][KD]
  unsigned short* eoutb = (unsigned short*)carve((size_t)(NS + NE)*KD*2);  // g0 layer-2 out (bf16)
  int* cnt_all = (int*)carve((size_t)3*NNODE*4);
  int* rp_all  = (int*)carve((size_t)3*RP*4);
  unsigned short* col_all = (unsigned short*)carve((size_t)3*NCSR*2);
  unsigned short* pWb = (unsigned short*)carve((size_t)3*KD*KD*2);  // bf16 head W x3
  float* rsp = (float*)carve((size_t)2*64*NS*4);   // rowsum partials
  float* csp = (float*)carve((size_t)2*64*NS*4);   // colsum partials
  float* dg_all = (float*)carve((size_t)2*NS*4);
  float* clbuf = (float*)carve(256);               // [0..31] partials, [32] counter
  unsigned short* Z = (unsigned short*)carve((size_t)2*8192*KD*2);  // bf16 Z1|Z2
  unsigned short* w2b = (unsigned short*)carve((size_t)KD*KD*2);    // bf16 W2^T [c][k]

  // ---- fused: CSR hist ∪ layer-1 fp32 GEMM (8-row blocks) ∪ weight converts ----
  k_fuse1<<<3*HB + NNODE/8 + 16 + 12, 256, 0, stream>>>(
      ep, part, W1, a1s, a1d, hb0, ss0, sd0,
      E_stu, E_exer, E_k, stu_ids, exer_ids, k_ids,
      pW1, pW2, pW3, pWb, W2, w2b);

  // ---- CSR scan chain (3 small kernels; machine-wide parallel) ----
  k_sumpart<<<(3*NNODE + 255)/256, 256, 0, stream>>>(part, cnt_all);
  k_scan<<<3, 1024, 0, stream>>>(cnt_all, rp_all);
  k_boff<<<(3*NNODE + 255)/256, 256, 0, stream>>>(part, rp_all, boff, clbuf);
  k_scatter<<<dim3(HB, 3), 256, 0, stream>>>(ep, boff, col_all);

  // ---- GAT layer 1 aggregation (batched) ----
  k_agg<<<3*NNODE/4, 256, 0, stream>>>(rp_all, col_all, hb0, ss0, sd0, etb,
                                       nullptr, nullptr, -1);

  // ---- GAT layer 2 (bf16 MFMA node GEMM; batched agg) ----
  k_mgemm<<<3*NNODE/128, 256, 0, stream>>>(etb, w2b, a2s, a2d, hb3, ss3, sd3);
  k_agg<<<3*NNODE/4, 256, 0, stream>>>(rp_all, col_all, hb3, ss3, sd3, nullptr,
                                       eoutb, Z, -2);

  // ---- fused: prediction head (256 blocks) ∥ sim GEMM (2048 blocks) ----
  k_simhead<<<BQ/32 + 2048, 256, 0, stream>>>(Z, rsp, csp, dg_all,
                                              pWb, pb3, kn_r, out, eoutb,
                                              stu_index, exer_index);

  // ---- closs reduce + deterministic last-block finalize ----
  k_lred<<<dim3(16, 2), 256, 0, stream>>>(rsp, csp, dg_all, out, clbuf);
}